// Round 3
// baseline (5246.944 us; speedup 1.0000x reference)
//
#include <hip/hip_runtime.h>
#include <cstddef>
#include <cstdint>

#define SCALE_QK 0.17677669529663687f   // 32^-0.5

// ---------------------------------------------------------------------------
// LayerNorm + window partition for a chunk of windows.
// rows ordered [b_local][s][n]; global window b_ = b0 + b_local
// ---------------------------------------------------------------------------
__global__ __launch_bounds__(256) void ln_part_kernel(
    const float* __restrict__ in, float* __restrict__ out,
    const float* __restrict__ gamma, const float* __restrict__ beta,
    int S, int b0) {
  int r = blockIdx.x;
  int n = r & 63;
  int tmp = r >> 6;
  int s = tmp % S;
  int b_ = b0 + tmp / S;
  int b  = b_ >> 6;
  int wh = (b_ >> 3) & 7;
  int ww = b_ & 7;
  int gh = wh * 8 + (n >> 3);
  int gw = ww * 8 + (n & 7);
  const float* src = in + (((size_t)(b * S + s) * 64 + gh) * 64 + gw) * 256;
  int c = threadIdx.x;
  float v = src[c];
  __shared__ float red[256];
  red[c] = v; __syncthreads();
  for (int off = 128; off > 0; off >>= 1) { if (c < off) red[c] += red[c + off]; __syncthreads(); }
  float mu = red[0] * (1.f / 256.f);
  __syncthreads();
  float dv = v - mu;
  red[c] = dv * dv; __syncthreads();
  for (int off = 128; off > 0; off >>= 1) { if (c < off) red[c] += red[c + off]; __syncthreads(); }
  float var = red[0] * (1.f / 256.f);
  out[(size_t)r * 256 + c] = dv * rsqrtf(var + 1e-5f) * gamma[c] + beta[c];
}

// Plain LayerNorm over rows of 256 (caller offsets `in` for chunking)
__global__ __launch_bounds__(256) void ln_plain_kernel(
    const float* __restrict__ in, float* __restrict__ out,
    const float* __restrict__ gamma, const float* __restrict__ beta) {
  int r = blockIdx.x;
  const float* src = in + (size_t)r * 256;
  int c = threadIdx.x;
  float v = src[c];
  __shared__ float red[256];
  red[c] = v; __syncthreads();
  for (int off = 128; off > 0; off >>= 1) { if (c < off) red[c] += red[c + off]; __syncthreads(); }
  float mu = red[0] * (1.f / 256.f);
  __syncthreads();
  float dv = v - mu;
  red[c] = dv * dv; __syncthreads();
  for (int off = 128; off > 0; off >>= 1) { if (c < off) red[c] += red[c + off]; __syncthreads(); }
  float var = red[0] * (1.f / 256.f);
  out[(size_t)r * 256 + c] = dv * rsqrtf(var + 1e-5f) * gamma[c] + beta[c];
}

// ---------------------------------------------------------------------------
// Generic f32 GEMM: C[M,N] = A[M,K] @ W[N,K]^T (+ bias) (+gelu) (+resid)
// ---------------------------------------------------------------------------
#define TBM 64
#define TBN 64
#define TBK 16
__global__ __launch_bounds__(256) void gemm_kernel(
    const float* __restrict__ A, const float* __restrict__ Wt,
    const float* __restrict__ bias, const float* __restrict__ resid,
    float* __restrict__ Cc, int Mrows, int Nout, int K, int epi) {
  __shared__ float As[TBK][TBM + 1];
  __shared__ float Ws[TBK][TBN + 1];
  int tid = threadIdx.x;
  int tx = tid & 15, ty = tid >> 4;
  int row0 = blockIdx.y * TBM, col0 = blockIdx.x * TBN;
  float acc[4][4] = {};
  for (int k0 = 0; k0 < K; k0 += TBK) {
    #pragma unroll
    for (int t = 0; t < 4; ++t) {
      int idx = t * 256 + tid;
      int lm = idx >> 4, lk = idx & 15;
      int gr = row0 + lm;
      As[lk][lm] = (gr < Mrows) ? A[(size_t)gr * K + k0 + lk] : 0.f;
      int gc = col0 + lm;
      Ws[lk][lm] = (gc < Nout) ? Wt[(size_t)gc * K + k0 + lk] : 0.f;
    }
    __syncthreads();
    #pragma unroll
    for (int kk = 0; kk < TBK; ++kk) {
      float a[4], b[4];
      #pragma unroll
      for (int i = 0; i < 4; ++i) a[i] = As[kk][ty * 4 + i];
      #pragma unroll
      for (int j = 0; j < 4; ++j) b[j] = Ws[kk][tx * 4 + j];
      #pragma unroll
      for (int i = 0; i < 4; ++i)
        #pragma unroll
        for (int j = 0; j < 4; ++j)
          acc[i][j] = fmaf(a[i], b[j], acc[i][j]);
    }
    __syncthreads();
  }
  #pragma unroll
  for (int i = 0; i < 4; ++i) {
    int gr = row0 + ty * 4 + i;
    if (gr >= Mrows) continue;
    #pragma unroll
    for (int j = 0; j < 4; ++j) {
      int gc = col0 + tx * 4 + j;
      if (gc >= Nout) continue;
      float v = acc[i][j] + (bias ? bias[gc] : 0.f);
      if (epi == 1) v = 0.5f * v * (1.f + erff(v * 0.70710678118654752f));
      if (resid) v += resid[(size_t)gr * Nout + gc];
      Cc[(size_t)gr * Nout + gc] = v;
    }
  }
}

// ---------------------------------------------------------------------------
// Window attention (chunk-local): one block per (b_l, t, m, h), 64 threads.
// Writes scrambled xw rows [(b_l*4+tp)*5+mp][np][cp].
// ---------------------------------------------------------------------------
__global__ __launch_bounds__(64) void wattn_kernel(
    const float* __restrict__ qb, const float* __restrict__ kvp,
    const float* __restrict__ rpb_table, float* __restrict__ xw) {
  int idx = blockIdx.x;
  int h = idx & 7; idx >>= 3;
  int m = idx % 5; idx /= 5;
  int t = idx & 3; int b_l = idx >> 2;
  int n = threadIdx.x;
  __shared__ float ks[64][33];
  __shared__ float vs[64][33];
  const float* krow = kvp + (((size_t)(b_l * 5 + m) * 64 + n) * 512) + h * 32;
  #pragma unroll
  for (int d = 0; d < 32; ++d) { ks[n][d] = krow[d]; vs[n][d] = krow[256 + d]; }
  float qr[32];
  const float* qrow = qb + (((size_t)(b_l * 4 + t) * 64 + n) * 256) + h * 32;
  #pragma unroll
  for (int d = 0; d < 32; ++d) qr[d] = qrow[d] * SCALE_QK;
  __syncthreads();
  int i1 = n >> 3, j1 = n & 7;
  float mx = -1e30f;
  for (int j = 0; j < 64; ++j) {
    float a = 0.f;
    #pragma unroll
    for (int d = 0; d < 32; ++d) a = fmaf(qr[d], ks[j][d], a);
    a += rpb_table[((i1 - (j >> 3) + 7) * 15 + (j1 - (j & 7) + 7)) * 8 + h];
    mx = fmaxf(mx, a);
  }
  float l = 0.f;
  float acc[32];
  #pragma unroll
  for (int d = 0; d < 32; ++d) acc[d] = 0.f;
  for (int j = 0; j < 64; ++j) {
    float a = 0.f;
    #pragma unroll
    for (int d = 0; d < 32; ++d) a = fmaf(qr[d], ks[j][d], a);
    a += rpb_table[((i1 - (j >> 3) + 7) * 15 + (j1 - (j & 7) + 7)) * 8 + h];
    float p = __expf(a - mx);
    l += p;
    #pragma unroll
    for (int d = 0; d < 32; ++d) acc[d] = fmaf(p, vs[j][d], acc[d]);
  }
  float inv = 1.f / l;
  // scramble: f=m*4+t -> t'=f/5, m'=f%5 ; n'=h*8+n/8 ; c'=(n%8)*32+d
  int f = m * 4 + t;
  int tp = f / 5, mp = f % 5;
  int np = h * 8 + (n >> 3);
  int cp = (n & 7) * 32;
  size_t base = ((((size_t)(b_l * 4 + tp) * 5 + mp) * 64 + np) * 256) + cp;
  #pragma unroll
  for (int d = 0; d < 32; ++d) xw[base + d] = acc[d] * inv;
}

// ---------------------------------------------------------------------------
// avg3: per (bp_l, n, c):
//   avgq = mean_m xw + pos_emb      (input to pq GEMM)
//   pka  = mean_m PK                (avg-token K, pos_pk added in pattn)
//   pva  = mean_m PV
// ---------------------------------------------------------------------------
__global__ __launch_bounds__(256) void avg3_kernel(
    const float* __restrict__ xw, const float* __restrict__ pk,
    const float* __restrict__ pv, const float* __restrict__ pos_emb,
    float* __restrict__ avgq, float* __restrict__ pka, float* __restrict__ pva) {
  int gid = blockIdx.x * 256 + threadIdx.x;
  int c = gid & 255;
  int rn = gid >> 8;          // bp_l*64 + n
  int n = rn & 63;
  int bp = rn >> 6;
  size_t base = ((size_t)bp * 320 + n) * 256 + c;   // row (bp*5+0)*64+n
  const size_t stride = 64 * 256;
  float sq = 0.f, sk = 0.f, sv = 0.f;
  #pragma unroll
  for (int m = 0; m < 5; ++m) {
    sq += xw[base + m * stride];
    sk += pk[base + m * stride];
    sv += pv[base + m * stride];
  }
  avgq[(size_t)rn * 256 + c] = sq * 0.2f + pos_emb[n * 256 + c];
  pka[(size_t)rn * 256 + c] = sk * 0.2f;
  pva[(size_t)rn * 256 + c] = sv * 0.2f;
}

// ---------------------------------------------------------------------------
// Pool attention (chunk-local): one block per (bp_l, h), 64 threads.
// 384 keys = [avg-token chunk] + 5 xw chunks; K/V = proj + pos_p{k,v}[n].
// ---------------------------------------------------------------------------
__global__ __launch_bounds__(64) void pattn_kernel(
    const float* __restrict__ pq, const float* __restrict__ pk,
    const float* __restrict__ pv, const float* __restrict__ pka,
    const float* __restrict__ pva, const float* __restrict__ pos_pk,
    const float* __restrict__ pos_pv, float* __restrict__ o) {
  int h = blockIdx.x & 7;
  int bp = blockIdx.x >> 3;
  int n = threadIdx.x;
  __shared__ float ks[64][33];
  __shared__ float vs[64][33];
  float qr[32];
  const float* qrow = pq + (((size_t)bp * 64 + n) * 256) + h * 32;
  #pragma unroll
  for (int d = 0; d < 32; ++d) qr[d] = qrow[d] * SCALE_QK;
  float ppk[32], ppv[32];
  #pragma unroll
  for (int d = 0; d < 32; ++d) {
    ppk[d] = pos_pk[n * 256 + h * 32 + d];
    ppv[d] = pos_pv[n * 256 + h * 32 + d];
  }
  float mx = -1e30f, l = 0.f;
  float acc[32];
  #pragma unroll
  for (int d = 0; d < 32; ++d) acc[d] = 0.f;
  for (int mm = 0; mm < 6; ++mm) {
    __syncthreads();
    const float* krow;
    const float* vrow;
    if (mm == 0) {
      krow = pka + (((size_t)bp * 64 + n) * 256) + h * 32;
      vrow = pva + (((size_t)bp * 64 + n) * 256) + h * 32;
    } else {
      krow = pk + (((size_t)(bp * 5 + mm - 1) * 64 + n) * 256) + h * 32;
      vrow = pv + (((size_t)(bp * 5 + mm - 1) * 64 + n) * 256) + h * 32;
    }
    #pragma unroll
    for (int d = 0; d < 32; ++d) { ks[n][d] = krow[d] + ppk[d]; vs[n][d] = vrow[d] + ppv[d]; }
    __syncthreads();
    float cmx = mx;
    for (int j = 0; j < 64; ++j) {
      float a = 0.f;
      #pragma unroll
      for (int d = 0; d < 32; ++d) a = fmaf(qr[d], ks[j][d], a);
      cmx = fmaxf(cmx, a);
    }
    float scale = __expf(mx - cmx);
    l *= scale;
    #pragma unroll
    for (int d = 0; d < 32; ++d) acc[d] *= scale;
    for (int j = 0; j < 64; ++j) {
      float a = 0.f;
      #pragma unroll
      for (int d = 0; d < 32; ++d) a = fmaf(qr[d], ks[j][d], a);
      float p = __expf(a - cmx);
      l += p;
      #pragma unroll
      for (int d = 0; d < 32; ++d) acc[d] = fmaf(p, vs[j][d], acc[d]);
    }
    mx = cmx;
  }
  float inv = 1.f / l;
  size_t base = (((size_t)bp * 64 + n) * 256) + h * 32;
  #pragma unroll
  for (int d = 0; d < 32; ++d) o[base + d] = acc[d] * inv;
}

// ---------------------------------------------------------------------------
// scatter: out[pixel] = x[pixel] + prj[(b_l*4+t)*64+n] (window reverse + resid)
// ---------------------------------------------------------------------------
__global__ __launch_bounds__(256) void scatter_kernel(
    const float* __restrict__ x, const float* __restrict__ prj,
    float* __restrict__ out, int b0) {
  int gid = blockIdx.x * 256 + threadIdx.x;
  int c = gid & 255;
  int r = gid >> 8;           // (b_l*4+t)*64+n
  int n = r & 63;
  int t = (r >> 6) & 3;
  int b_l = r >> 8;
  int b_ = b0 + b_l;
  int b = b_ >> 6, wh = (b_ >> 3) & 7, ww = b_ & 7;
  int gh = wh * 8 + (n >> 3), gw = ww * 8 + (n & 7);
  size_t pix = (((size_t)(b * 4 + t) * 64 + gh) * 64 + gw) * 256 + c;
  out[pix] = x[pix] + prj[(size_t)r * 256 + c];
}

// ---------------------------------------------------------------------------
// Launch
// ---------------------------------------------------------------------------
extern "C" void kernel_launch(void* const* d_in, const int* in_sizes, int n_in,
                              void* d_out, int out_size, void* d_ws, size_t ws_size,
                              hipStream_t stream) {
  const float* x       = (const float*)d_in[0];
  const float* kv      = (const float*)d_in[1];
  const float* nq_g    = (const float*)d_in[3];
  const float* nq_b    = (const float*)d_in[4];
  const float* nk_g    = (const float*)d_in[5];
  const float* nk_b    = (const float*)d_in[6];
  const float* q_w     = (const float*)d_in[7];
  const float* q_b     = (const float*)d_in[8];
  const float* kv_w    = (const float*)d_in[9];
  const float* kv_b    = (const float*)d_in[10];
  const float* rpb     = (const float*)d_in[11];
  const float* pos_emb = (const float*)d_in[12];
  const float* pq_w    = (const float*)d_in[13];
  const float* pq_b    = (const float*)d_in[14];
  const float* pk_w    = (const float*)d_in[15];
  const float* pk_b    = (const float*)d_in[16];
  const float* pv_w    = (const float*)d_in[17];
  const float* pv_b    = (const float*)d_in[18];
  const float* po_w    = (const float*)d_in[19];
  const float* po_b    = (const float*)d_in[20];
  const float* proj_w  = (const float*)d_in[21];
  const float* proj_b  = (const float*)d_in[22];
  const float* n2_g    = (const float*)d_in[23];
  const float* n2_b    = (const float*)d_in[24];
  const float* mlp_w1  = (const float*)d_in[25];
  const float* mlp_b1  = (const float*)d_in[26];
  const float* mlp_w2  = (const float*)d_in[27];
  const float* mlp_b2  = (const float*)d_in[28];
  float* out = (float*)d_out;
  float* ws = (float*)d_ws;

  // Adaptive chunk size: per-chunk footprint = 1,441,792*CH floats (+32K pos)
  size_t wsF = ws_size / sizeof(float);
  int CH = 0;
  const int cands[7] = {64, 32, 16, 8, 4, 2, 1};
  for (int i = 0; i < 7; ++i) {
    size_t need = 32768 + (size_t)1441792 * cands[i];
    if (need <= wsF) { CH = cands[i]; break; }
  }
  if (CH == 0) return;   // ws too small even for CH=1 (5.9 MB): launch nothing
  size_t CHs = (size_t)CH;

  float* pospk = ws;
  float* pospv = ws + 16384;
  float* cb    = ws + 32768;           // chunk region base
  // regionA [0, 655360CH): PK | PV ; early aliases qw|qbuf|kvw|kvp
  float* PK  = cb;
  float* PV  = cb + 327680 * CHs;
  float* qw  = cb;
  float* qb2 = cb + 65536 * CHs;
  float* kvw = cb + 131072 * CHs;
  float* kvp = cb + 212992 * CHs;
  // regionB: xw
  float* xw  = cb + 655360 * CHs;
  // regionC: smalls
  float* AVG = cb + 983040 * CHs;
  float* PQ  = AVG + 65536 * CHs;
  float* PKA = PQ  + 65536 * CHs;
  float* PVA = PKA + 65536 * CHs;
  float* OC  = PVA + 65536 * CHs;
  float* PG  = OC  + 65536 * CHs;
  float* PRJ = PG  + 65536 * CHs;

  // pos token projections: pos_pk = pos_emb @ pk_w.T + pk_b (64x256), same pv
  gemm_kernel<<<dim3(4, 1), 256, 0, stream>>>(pos_emb, pk_w, pk_b, nullptr, pospk, 64, 256, 256, 0);
  gemm_kernel<<<dim3(4, 1), 256, 0, stream>>>(pos_emb, pv_w, pv_b, nullptr, pospv, 64, 256, 256, 0);

  for (int c0 = 0; c0 < 128; c0 += CH) {
    int rowsQ  = CH * 4 * 64;
    int rowsKV = CH * 5 * 64;
    int rowsXW = CH * 1280;      // bpC*5*64
    int bpC    = CH * 4;
    ln_part_kernel<<<rowsQ, 256, 0, stream>>>(x, qw, nq_g, nq_b, 4, c0);
    ln_part_kernel<<<rowsKV, 256, 0, stream>>>(kv, kvw, nk_g, nk_b, 5, c0);
    gemm_kernel<<<dim3(4, rowsQ / 64), 256, 0, stream>>>(qw, q_w, q_b, nullptr, qb2, rowsQ, 256, 256, 0);
    gemm_kernel<<<dim3(8, rowsKV / 64), 256, 0, stream>>>(kvw, kv_w, kv_b, nullptr, kvp, rowsKV, 512, 256, 0);
    wattn_kernel<<<CH * 160, 64, 0, stream>>>(qb2, kvp, rpb, xw);
    gemm_kernel<<<dim3(4, rowsXW / 64), 256, 0, stream>>>(xw, pk_w, nullptr, nullptr, PK, rowsXW, 256, 256, 0);
    gemm_kernel<<<dim3(4, rowsXW / 64), 256, 0, stream>>>(xw, pv_w, nullptr, nullptr, PV, rowsXW, 256, 256, 0);
    avg3_kernel<<<bpC * 64, 256, 0, stream>>>(xw, PK, PV, pos_emb, AVG, PKA, PVA);
    gemm_kernel<<<dim3(4, bpC), 256, 0, stream>>>(AVG, pq_w, pq_b, nullptr, PQ, bpC * 64, 256, 256, 0);
    pattn_kernel<<<bpC * 8, 64, 0, stream>>>(PQ, PK, PV, PKA, PVA, pospk, pospv, OC);
    gemm_kernel<<<dim3(4, bpC), 256, 0, stream>>>(OC, po_w, po_b, nullptr, PG, bpC * 64, 256, 256, 1);
    gemm_kernel<<<dim3(4, bpC), 256, 0, stream>>>(PG, proj_w, proj_b, nullptr, PRJ, bpC * 64, 256, 256, 0);
    scatter_kernel<<<bpC * 64, 256, 0, stream>>>(x, PRJ, out, c0);
  }

  // MLP over x1 (stored in `out`), chunked by rows
  int R = 32768;
  while ((size_t)R * 1280 > (size_t)1441792 * CHs && R > 64) R >>= 1;
  float* ln2c = cb;
  float* h1c  = cb + (size_t)R * 256;
  for (int r0 = 0; r0 < 32768; r0 += R) {
    ln_plain_kernel<<<R, 256, 0, stream>>>(out + (size_t)r0 * 256, ln2c, n2_g, n2_b);
    gemm_kernel<<<dim3(16, R / 64), 256, 0, stream>>>(ln2c, mlp_w1, mlp_b1, nullptr, h1c, R, 1024, 256, 1);
    gemm_kernel<<<dim3(4, R / 64), 256, 0, stream>>>(h1c, mlp_w2, mlp_b2, out + (size_t)r0 * 256,
                                                     out + (size_t)r0 * 256, R, 256, 1024, 0);
  }
}

// Round 6
// 3143.924 us; speedup vs baseline: 1.6689x; 1.6689x over previous
//
#include <hip/hip_runtime.h>
#include <hip/hip_bf16.h>
#include <cstddef>
#include <cstdint>

#define SCALE_QK 0.17677669529663687f   // 32^-0.5

typedef __attribute__((ext_vector_type(8))) short bf16x8;
typedef __attribute__((ext_vector_type(4))) float f32x4;

// ---------------------------------------------------------------------------
// f32 -> bf16 conversion (weights)
// ---------------------------------------------------------------------------
__global__ __launch_bounds__(256) void convb_kernel(
    const float* __restrict__ src, __hip_bfloat16* __restrict__ dst, int n) {
  int i = blockIdx.x * 256 + threadIdx.x;
  if (i < n) dst[i] = __float2bfloat16(src[i]);
}

// ---------------------------------------------------------------------------
// LayerNorm + window partition -> bf16 rows
// ---------------------------------------------------------------------------
__global__ __launch_bounds__(256) void ln_part_kernel(
    const float* __restrict__ in, __hip_bfloat16* __restrict__ out,
    const float* __restrict__ gamma, const float* __restrict__ beta,
    int S, int b0) {
  int r = blockIdx.x;
  int n = r & 63;
  int tmp = r >> 6;
  int s = tmp % S;
  int b_ = b0 + tmp / S;
  int b  = b_ >> 6;
  int wh = (b_ >> 3) & 7;
  int ww = b_ & 7;
  int gh = wh * 8 + (n >> 3);
  int gw = ww * 8 + (n & 7);
  const float* src = in + (((size_t)(b * S + s) * 64 + gh) * 64 + gw) * 256;
  int c = threadIdx.x;
  float v = src[c];
  __shared__ float red[256];
  red[c] = v; __syncthreads();
  for (int off = 128; off > 0; off >>= 1) { if (c < off) red[c] += red[c + off]; __syncthreads(); }
  float mu = red[0] * (1.f / 256.f);
  __syncthreads();
  float dv = v - mu;
  red[c] = dv * dv; __syncthreads();
  for (int off = 128; off > 0; off >>= 1) { if (c < off) red[c] += red[c + off]; __syncthreads(); }
  float var = red[0] * (1.f / 256.f);
  out[(size_t)r * 256 + c] = __float2bfloat16(dv * rsqrtf(var + 1e-5f) * gamma[c] + beta[c]);
}

// Plain LayerNorm (f32 in) -> bf16 out
__global__ __launch_bounds__(256) void ln_plain_kernel(
    const float* __restrict__ in, __hip_bfloat16* __restrict__ out,
    const float* __restrict__ gamma, const float* __restrict__ beta) {
  int r = blockIdx.x;
  const float* src = in + (size_t)r * 256;
  int c = threadIdx.x;
  float v = src[c];
  __shared__ float red[256];
  red[c] = v; __syncthreads();
  for (int off = 128; off > 0; off >>= 1) { if (c < off) red[c] += red[c + off]; __syncthreads(); }
  float mu = red[0] * (1.f / 256.f);
  __syncthreads();
  float dv = v - mu;
  red[c] = dv * dv; __syncthreads();
  for (int off = 128; off > 0; off >>= 1) { if (c < off) red[c] += red[c + off]; __syncthreads(); }
  float var = red[0] * (1.f / 256.f);
  out[(size_t)r * 256 + c] = __float2bfloat16(dv * rsqrtf(var + 1e-5f) * gamma[c] + beta[c]);
}

// ---------------------------------------------------------------------------
// bf16 MFMA GEMM: C[M,N] = A[M,K](bf16) @ W[N,K](bf16)^T (+ bias)
// 128x128 tile, BK=64, 4 waves (2x2 of 64x64), 16x16x32 MFMA, XOR-swizzled LDS.
// flags: bit0 = gelu, bit1 = bf16 output. resid (f32) optional, f32-out only.
// Requires: N%128==0, K%64==0. M guarded (stage rows clamped, writes guarded).
// ---------------------------------------------------------------------------
__global__ __launch_bounds__(256) void mgemm_kernel(
    const ushort* __restrict__ A, const ushort* __restrict__ W,
    const float* __restrict__ bias, const float* __restrict__ resid,
    void* __restrict__ Cp, int Mrows, int N, int K, int flags) {
  __shared__ ushort As[128 * 64];
  __shared__ ushort Bs[128 * 64];
  int tid = threadIdx.x;
  int lane = tid & 63, wid = tid >> 6;
  int wm = wid >> 1, wn = wid & 1;
  int row0 = blockIdx.y * 128, col0 = blockIdx.x * 128;
  int srow = tid >> 3;           // 0..31
  int slot = tid & 7;            // 16B slot within 128B row
  f32x4 acc[4][4];
  #pragma unroll
  for (int m = 0; m < 4; ++m)
    #pragma unroll
    for (int n = 0; n < 4; ++n) acc[m][n] = (f32x4){0.f, 0.f, 0.f, 0.f};

  for (int k0 = 0; k0 < K; k0 += 64) {
    #pragma unroll
    for (int i = 0; i < 4; ++i) {
      int r = i * 32 + srow;
      int gr = row0 + r; if (gr >= Mrows) gr = Mrows - 1;
      bf16x8 va = *(const bf16x8*)(A + (size_t)gr * K + k0 + slot * 8);
      int gc = col0 + r;         // N%128==0 -> always in range
      bf16x8 vb = *(const bf16x8*)(W + (size_t)gc * K + k0 + slot * 8);
      int ldso = r * 64 + ((slot ^ (r & 7)) << 3);
      *(bf16x8*)(As + ldso) = va;
      *(bf16x8*)(Bs + ldso) = vb;
    }
    __syncthreads();
    #pragma unroll
    for (int ks = 0; ks < 2; ++ks) {
      bf16x8 af[4], bfr[4];
      int sgrp = ks * 4 + (lane >> 4);
      #pragma unroll
      for (int m = 0; m < 4; ++m) {
        int r = wm * 64 + m * 16 + (lane & 15);
        af[m] = *(const bf16x8*)(As + r * 64 + ((sgrp ^ (r & 7)) << 3));
      }
      #pragma unroll
      for (int n = 0; n < 4; ++n) {
        int r = wn * 64 + n * 16 + (lane & 15);
        bfr[n] = *(const bf16x8*)(Bs + r * 64 + ((sgrp ^ (r & 7)) << 3));
      }
      #pragma unroll
      for (int m = 0; m < 4; ++m)
        #pragma unroll
        for (int n = 0; n < 4; ++n)
          acc[m][n] = __builtin_amdgcn_mfma_f32_16x16x32_bf16(af[m], bfr[n], acc[m][n], 0, 0, 0);
    }
    __syncthreads();
  }

  // epilogue: C/D layout col=lane&15, row=(lane>>4)*4+reg
  float* Cf = (float*)Cp;
  __hip_bfloat16* Cb = (__hip_bfloat16*)Cp;
  #pragma unroll
  for (int m = 0; m < 4; ++m) {
    #pragma unroll
    for (int n = 0; n < 4; ++n) {
      int col = col0 + wn * 64 + n * 16 + (lane & 15);
      #pragma unroll
      for (int r = 0; r < 4; ++r) {
        int row = row0 + wm * 64 + m * 16 + (lane >> 4) * 4 + r;
        if (row >= Mrows) continue;
        float v = acc[m][n][r] + (bias ? bias[col] : 0.f);
        if (flags & 1) v = 0.5f * v * (1.f + erff(v * 0.70710678118654752f));
        if (resid) v += resid[(size_t)row * N + col];
        if (flags & 2) Cb[(size_t)row * N + col] = __float2bfloat16(v);
        else           Cf[(size_t)row * N + col] = v;
      }
    }
  }
}

// ---------------------------------------------------------------------------
// f32 GEMM (kept for the tiny 64-row pos_emb projections)
// ---------------------------------------------------------------------------
#define TBM 64
#define TBN 64
#define TBK 16
__global__ __launch_bounds__(256) void gemm_kernel(
    const float* __restrict__ A, const float* __restrict__ Wt,
    const float* __restrict__ bias, float* __restrict__ Cc,
    int Mrows, int Nout, int K) {
  __shared__ float Asl[TBK][TBM + 1];
  __shared__ float Wsl[TBK][TBN + 1];
  int tid = threadIdx.x;
  int tx = tid & 15, ty = tid >> 4;
  int row0 = blockIdx.y * TBM, col0 = blockIdx.x * TBN;
  float acc[4][4] = {};
  for (int k0 = 0; k0 < K; k0 += TBK) {
    #pragma unroll
    for (int t = 0; t < 4; ++t) {
      int idx = t * 256 + tid;
      int lm = idx >> 4, lk = idx & 15;
      int gr = row0 + lm;
      Asl[lk][lm] = (gr < Mrows) ? A[(size_t)gr * K + k0 + lk] : 0.f;
      int gc = col0 + lm;
      Wsl[lk][lm] = (gc < Nout) ? Wt[(size_t)gc * K + k0 + lk] : 0.f;
    }
    __syncthreads();
    #pragma unroll
    for (int kk = 0; kk < TBK; ++kk) {
      float a[4], b[4];
      #pragma unroll
      for (int i = 0; i < 4; ++i) a[i] = Asl[kk][ty * 4 + i];
      #pragma unroll
      for (int j = 0; j < 4; ++j) b[j] = Wsl[kk][tx * 4 + j];
      #pragma unroll
      for (int i = 0; i < 4; ++i)
        #pragma unroll
        for (int j = 0; j < 4; ++j)
          acc[i][j] = fmaf(a[i], b[j], acc[i][j]);
    }
    __syncthreads();
  }
  #pragma unroll
  for (int i = 0; i < 4; ++i) {
    int gr = row0 + ty * 4 + i;
    if (gr >= Mrows) continue;
    #pragma unroll
    for (int j = 0; j < 4; ++j) {
      int gc = col0 + tx * 4 + j;
      if (gc >= Nout) continue;
      Cc[(size_t)gr * Nout + gc] = acc[i][j] + bias[gc];
    }
  }
}

// ---------------------------------------------------------------------------
// Window attention: one block per (b_l, t, m, h), 64 threads. f32 in, bf16 out.
// ---------------------------------------------------------------------------
__global__ __launch_bounds__(64) void wattn_kernel(
    const float* __restrict__ qb, const float* __restrict__ kvp,
    const float* __restrict__ rpb_table, __hip_bfloat16* __restrict__ xw) {
  int idx = blockIdx.x;
  int h = idx & 7; idx >>= 3;
  int m = idx % 5; idx /= 5;
  int t = idx & 3; int b_l = idx >> 2;
  int n = threadIdx.x;
  __shared__ float ks[64][33];
  __shared__ float vs[64][33];
  const float* krow = kvp + (((size_t)(b_l * 5 + m) * 64 + n) * 512) + h * 32;
  #pragma unroll
  for (int d = 0; d < 32; ++d) { ks[n][d] = krow[d]; vs[n][d] = krow[256 + d]; }
  float qr[32];
  const float* qrow = qb + (((size_t)(b_l * 4 + t) * 64 + n) * 256) + h * 32;
  #pragma unroll
  for (int d = 0; d < 32; ++d) qr[d] = qrow[d] * SCALE_QK;
  __syncthreads();
  int i1 = n >> 3, j1 = n & 7;
  float mx = -1e30f;
  for (int j = 0; j < 64; ++j) {
    float a = 0.f;
    #pragma unroll
    for (int d = 0; d < 32; ++d) a = fmaf(qr[d], ks[j][d], a);
    a += rpb_table[((i1 - (j >> 3) + 7) * 15 + (j1 - (j & 7) + 7)) * 8 + h];
    mx = fmaxf(mx, a);
  }
  float l = 0.f;
  float acc[32];
  #pragma unroll
  for (int d = 0; d < 32; ++d) acc[d] = 0.f;
  for (int j = 0; j < 64; ++j) {
    float a = 0.f;
    #pragma unroll
    for (int d = 0; d < 32; ++d) a = fmaf(qr[d], ks[j][d], a);
    a += rpb_table[((i1 - (j >> 3) + 7) * 15 + (j1 - (j & 7) + 7)) * 8 + h];
    float p = __expf(a - mx);
    l += p;
    #pragma unroll
    for (int d = 0; d < 32; ++d) acc[d] = fmaf(p, vs[j][d], acc[d]);
  }
  float inv = 1.f / l;
  // scramble: f=m*4+t -> tp=f/5, mp=f%5 ; np=h*8+n/8 ; cp=(n%8)*32+d
  int f = m * 4 + t;
  int tp = f / 5, mp = f % 5;
  int np = h * 8 + (n >> 3);
  int cp = (n & 7) * 32;
  size_t base = ((((size_t)(b_l * 4 + tp) * 5 + mp) * 64 + np) * 256) + cp;
  #pragma unroll
  for (int d = 0; d < 32; ++d) xw[base + d] = __float2bfloat16(acc[d] * inv);
}

// ---------------------------------------------------------------------------
// avg3: avgq(bf16) = mean_m xw + pos ; pka/pva(f32) = mean_m PK/PV
// ---------------------------------------------------------------------------
__global__ __launch_bounds__(256) void avg3_kernel(
    const __hip_bfloat16* __restrict__ xw, const float* __restrict__ pk,
    const float* __restrict__ pv, const float* __restrict__ pos_emb,
    __hip_bfloat16* __restrict__ avgq, float* __restrict__ pka,
    float* __restrict__ pva) {
  int gid = blockIdx.x * 256 + threadIdx.x;
  int c = gid & 255;
  int rn = gid >> 8;          // bp_l*64 + n
  int n = rn & 63;
  int bp = rn >> 6;
  size_t base = ((size_t)bp * 320 + n) * 256 + c;
  const size_t stride = 64 * 256;
  float sq = 0.f, sk = 0.f, sv = 0.f;
  #pragma unroll
  for (int m = 0; m < 5; ++m) {
    sq += __bfloat162float(xw[base + m * stride]);
    sk += pk[base + m * stride];
    sv += pv[base + m * stride];
  }
  avgq[(size_t)rn * 256 + c] = __float2bfloat16(sq * 0.2f + pos_emb[n * 256 + c]);
  pka[(size_t)rn * 256 + c] = sk * 0.2f;
  pva[(size_t)rn * 256 + c] = sv * 0.2f;
}

// ---------------------------------------------------------------------------
// Pool attention: one block per (bp_l, h). f32 in, bf16 out.
// ---------------------------------------------------------------------------
__global__ __launch_bounds__(64) void pattn_kernel(
    const float* __restrict__ pq, const float* __restrict__ pk,
    const float* __restrict__ pv, const float* __restrict__ pka,
    const float* __restrict__ pva, const float* __restrict__ pos_pk,
    const float* __restrict__ pos_pv, __hip_bfloat16* __restrict__ o) {
  int h = blockIdx.x & 7;
  int bp = blockIdx.x >> 3;
  int n = threadIdx.x;
  __shared__ float ks[64][33];
  __shared__ float vs[64][33];
  float qr[32];
  const float* qrow = pq + (((size_t)bp * 64 + n) * 256) + h * 32;
  #pragma unroll
  for (int d = 0; d < 32; ++d) qr[d] = qrow[d] * SCALE_QK;
  float ppk[32], ppv[32];
  #pragma unroll
  for (int d = 0; d < 32; ++d) {
    ppk[d] = pos_pk[n * 256 + h * 32 + d];
    ppv[d] = pos_pv[n * 256 + h * 32 + d];
  }
  float mx = -1e30f, l = 0.f;
  float acc[32];
  #pragma unroll
  for (int d = 0; d < 32; ++d) acc[d] = 0.f;
  for (int mm = 0; mm < 6; ++mm) {
    __syncthreads();
    const float* krow;
    const float* vrow;
    if (mm == 0) {
      krow = pka + (((size_t)bp * 64 + n) * 256) + h * 32;
      vrow = pva + (((size_t)bp * 64 + n) * 256) + h * 32;
    } else {
      krow = pk + (((size_t)(bp * 5 + mm - 1) * 64 + n) * 256) + h * 32;
      vrow = pv + (((size_t)(bp * 5 + mm - 1) * 64 + n) * 256) + h * 32;
    }
    #pragma unroll
    for (int d = 0; d < 32; ++d) { ks[n][d] = krow[d] + ppk[d]; vs[n][d] = vrow[d] + ppv[d]; }
    __syncthreads();
    float cmx = mx;
    for (int j = 0; j < 64; ++j) {
      float a = 0.f;
      #pragma unroll
      for (int d = 0; d < 32; ++d) a = fmaf(qr[d], ks[j][d], a);
      cmx = fmaxf(cmx, a);
    }
    float scale = __expf(mx - cmx);
    l *= scale;
    #pragma unroll
    for (int d = 0; d < 32; ++d) acc[d] *= scale;
    for (int j = 0; j < 64; ++j) {
      float a = 0.f;
      #pragma unroll
      for (int d = 0; d < 32; ++d) a = fmaf(qr[d], ks[j][d], a);
      float p = __expf(a - cmx);
      l += p;
      #pragma unroll
      for (int d = 0; d < 32; ++d) acc[d] = fmaf(p, vs[j][d], acc[d]);
    }
    mx = cmx;
  }
  float inv = 1.f / l;
  size_t base = (((size_t)bp * 64 + n) * 256) + h * 32;
  #pragma unroll
  for (int d = 0; d < 32; ++d) o[base + d] = __float2bfloat16(acc[d] * inv);
}

// ---------------------------------------------------------------------------
// scatter: out[pixel] = x[pixel] + prj[row]  (window reverse + residual)
// ---------------------------------------------------------------------------
__global__ __launch_bounds__(256) void scatter_kernel(
    const float* __restrict__ x, const float* __restrict__ prj,
    float* __restrict__ out, int b0) {
  int gid = blockIdx.x * 256 + threadIdx.x;
  int c = gid & 255;
  int r = gid >> 8;
  int n = r & 63;
  int t = (r >> 6) & 3;
  int b_l = r >> 8;
  int b_ = b0 + b_l;
  int b = b_ >> 6, wh = (b_ >> 3) & 7, ww = b_ & 7;
  int gh = wh * 8 + (n >> 3), gw = ww * 8 + (n & 7);
  size_t pix = (((size_t)(b * 4 + t) * 64 + gh) * 64 + gw) * 256 + c;
  out[pix] = x[pix] + prj[(size_t)r * 256 + c];
}

// ---------------------------------------------------------------------------
// Launch
// ---------------------------------------------------------------------------
extern "C" void kernel_launch(void* const* d_in, const int* in_sizes, int n_in,
                              void* d_out, int out_size, void* d_ws, size_t ws_size,
                              hipStream_t stream) {
  const float* x       = (const float*)d_in[0];
  const float* kv      = (const float*)d_in[1];
  const float* nq_g    = (const float*)d_in[3];
  const float* nq_b    = (const float*)d_in[4];
  const float* nk_g    = (const float*)d_in[5];
  const float* nk_b    = (const float*)d_in[6];
  const float* q_w     = (const float*)d_in[7];
  const float* q_b     = (const float*)d_in[8];
  const float* kv_w    = (const float*)d_in[9];
  const float* kv_b    = (const float*)d_in[10];
  const float* rpb     = (const float*)d_in[11];
  const float* pos_emb = (const float*)d_in[12];
  const float* pq_w    = (const float*)d_in[13];
  const float* pq_b    = (const float*)d_in[14];
  const float* pk_w    = (const float*)d_in[15];
  const float* pk_b    = (const float*)d_in[16];
  const float* pv_w    = (const float*)d_in[17];
  const float* pv_b    = (const float*)d_in[18];
  const float* po_w    = (const float*)d_in[19];
  const float* po_b    = (const float*)d_in[20];
  const float* proj_w  = (const float*)d_in[21];
  const float* proj_b  = (const float*)d_in[22];
  const float* n2_g    = (const float*)d_in[23];
  const float* n2_b    = (const float*)d_in[24];
  const float* mlp_w1  = (const float*)d_in[25];
  const float* mlp_b1  = (const float*)d_in[26];
  const float* mlp_w2  = (const float*)d_in[27];
  const float* mlp_b2  = (const float*)d_in[28];
  float* out = (float*)d_out;
  float* ws = (float*)d_ws;

  // ---- fixed region: pos projections (f32) + bf16 weights ----
  size_t wsF = ws_size / sizeof(float);
  float* pospk = ws;                 // 16384 f
  float* pospv = ws + 16384;         // 16384 f
  __hip_bfloat16* wq_b    = (__hip_bfloat16*)(ws + 32768);    // 65536 e
  __hip_bfloat16* wkv_b   = (__hip_bfloat16*)(ws + 65536);    // 131072 e
  __hip_bfloat16* wpq_b   = (__hip_bfloat16*)(ws + 131072);
  __hip_bfloat16* wpk_b   = (__hip_bfloat16*)(ws + 163840);
  __hip_bfloat16* wpv_b   = (__hip_bfloat16*)(ws + 196608);
  __hip_bfloat16* wpo_b   = (__hip_bfloat16*)(ws + 229376);
  __hip_bfloat16* wproj_b = (__hip_bfloat16*)(ws + 262144);
  __hip_bfloat16* wm1_b   = (__hip_bfloat16*)(ws + 294912);   // 262144 e
  __hip_bfloat16* wm2_b   = (__hip_bfloat16*)(ws + 425984);   // 262144 e
  const size_t FIXED = 557056;

  // ---- adaptive chunking: per-chunk footprint 1,179,648*CH floats ----
  int CH = 0;
  const int cands[7] = {64, 32, 16, 8, 4, 2, 1};
  for (int i = 0; i < 7; ++i) {
    size_t need = FIXED + (size_t)1179648 * cands[i];
    if (need <= wsF) { CH = cands[i]; break; }
  }
  if (CH == 0) return;
  size_t CHs = (size_t)CH;
  float* cb = ws + FIXED;

  __hip_bfloat16* qw_b  = (__hip_bfloat16*)cb;                       // 65536CH e
  __hip_bfloat16* kvw_b = (__hip_bfloat16*)(cb + 32768 * CHs);       // 81920CH e
  float* qb2 = cb + 73728 * CHs;                                     // 65536CH f
  float* kvp = cb + 139264 * CHs;                                    // 163840CH f
  float* PK  = cb;                                                   // 327680CH f (reuse)
  float* PV  = cb + 327680 * CHs;                                    // 327680CH f
  __hip_bfloat16* xw_b  = (__hip_bfloat16*)(cb + 655360 * CHs);      // 327680CH e
  __hip_bfloat16* AVG_b = (__hip_bfloat16*)(cb + 819200 * CHs);      // 65536CH e
  float* PQ  = cb + 851968 * CHs;                                    // 65536CH f
  float* PKA = cb + 917504 * CHs;
  float* PVA = cb + 983040 * CHs;
  __hip_bfloat16* OC_b = (__hip_bfloat16*)(cb + 1048576 * CHs);
  __hip_bfloat16* PG_b = (__hip_bfloat16*)(cb + 1081344 * CHs);
  float* PRJ = cb + 1114112 * CHs;

  // ---- one-time: pos projections (f32) + weight conversions ----
  gemm_kernel<<<dim3(4, 1), 256, 0, stream>>>(pos_emb, pk_w, pk_b, pospk, 64, 256, 256);
  gemm_kernel<<<dim3(4, 1), 256, 0, stream>>>(pos_emb, pv_w, pv_b, pospv, 64, 256, 256);
  convb_kernel<<<256,  256, 0, stream>>>(q_w,    wq_b,    65536);
  convb_kernel<<<512,  256, 0, stream>>>(kv_w,   wkv_b,   131072);
  convb_kernel<<<256,  256, 0, stream>>>(pq_w,   wpq_b,   65536);
  convb_kernel<<<256,  256, 0, stream>>>(pk_w,   wpk_b,   65536);
  convb_kernel<<<256,  256, 0, stream>>>(pv_w,   wpv_b,   65536);
  convb_kernel<<<256,  256, 0, stream>>>(po_w,   wpo_b,   65536);
  convb_kernel<<<256,  256, 0, stream>>>(proj_w, wproj_b, 65536);
  convb_kernel<<<1024, 256, 0, stream>>>(mlp_w1, wm1_b,   262144);
  convb_kernel<<<1024, 256, 0, stream>>>(mlp_w2, wm2_b,   262144);

  for (int c0 = 0; c0 < 128; c0 += CH) {
    int rowsQ  = CH * 256;
    int rowsKV = CH * 320;
    int rowsXW = CH * 1280;
    int bpC    = CH * 4;
    int rowsP  = bpC * 64;    // = rowsQ
    ln_part_kernel<<<rowsQ, 256, 0, stream>>>(x, qw_b, nq_g, nq_b, 4, c0);
    ln_part_kernel<<<rowsKV, 256, 0, stream>>>(kv, kvw_b, nk_g, nk_b, 5, c0);
    mgemm_kernel<<<dim3(2, rowsQ / 128), 256, 0, stream>>>(
        (const ushort*)qw_b, (const ushort*)wq_b, q_b, nullptr, qb2, rowsQ, 256, 256, 0);
    mgemm_kernel<<<dim3(4, (rowsKV + 127) / 128), 256, 0, stream>>>(
        (const ushort*)kvw_b, (const ushort*)wkv_b, kv_b, nullptr, kvp, rowsKV, 512, 256, 0);
    wattn_kernel<<<CH * 160, 64, 0, stream>>>(qb2, kvp, rpb, xw_b);
    mgemm_kernel<<<dim3(2, rowsXW / 128), 256, 0, stream>>>(
        (const ushort*)xw_b, (const ushort*)wpk_b, nullptr, nullptr, PK, rowsXW, 256, 256, 0);
    mgemm_kernel<<<dim3(2, rowsXW / 128), 256, 0, stream>>>(
        (const ushort*)xw_b, (const ushort*)wpv_b, nullptr, nullptr, PV, rowsXW, 256, 256, 0);
    avg3_kernel<<<rowsP, 256, 0, stream>>>(xw_b, PK, PV, pos_emb, AVG_b, PKA, PVA);
    mgemm_kernel<<<dim3(2, rowsP / 128), 256, 0, stream>>>(
        (const ushort*)AVG_b, (const ushort*)wpq_b, pq_b, nullptr, PQ, rowsP, 256, 256, 0);
    pattn_kernel<<<bpC * 8, 64, 0, stream>>>(PQ, PK, PV, PKA, PVA, pospk, pospv, OC_b);
    mgemm_kernel<<<dim3(2, rowsP / 128), 256, 0, stream>>>(
        (const ushort*)OC_b, (const ushort*)wpo_b, po_b, nullptr, PG_b, rowsP, 256, 256, 3);
    mgemm_kernel<<<dim3(2, rowsP / 128), 256, 0, stream>>>(
        (const ushort*)PG_b, (const ushort*)wproj_b, proj_b, nullptr, PRJ, rowsP, 256, 256, 0);
    scatter_kernel<<<rowsP, 256, 0, stream>>>(x, PRJ, out, c0);
  }

  // ---- MLP over x1 (in d_out), chunked by rows ----
  int R = 32768;
  while ((size_t)R * 640 > (size_t)1179648 * CHs && R > 128) R >>= 1;
  __hip_bfloat16* ln2c = (__hip_bfloat16*)cb;                      // R*256 e
  __hip_bfloat16* h1c  = (__hip_bfloat16*)(cb + 128 * (size_t)R);  // R*1024 e
  for (int r0 = 0; r0 < 32768; r0 += R) {
    ln_plain_kernel<<<R, 256, 0, stream>>>(out + (size_t)r0 * 256, ln2c, n2_g, n2_b);
    mgemm_kernel<<<dim3(8, R / 128), 256, 0, stream>>>(
        (const ushort*)ln2c, (const ushort*)wm1_b, mlp_b1, nullptr, h1c, R, 1024, 256, 3);
    mgemm_kernel<<<dim3(2, R / 128), 256, 0, stream>>>(
        (const ushort*)h1c, (const ushort*)wm2_b, mlp_b2, out + (size_t)r0 * 256,
        out + (size_t)r0 * 256, R, 256, 1024, 0);
  }
}

// Round 7
// 2283.085 us; speedup vs baseline: 2.2982x; 1.3771x over previous
//
#include <hip/hip_runtime.h>
#include <hip/hip_bf16.h>
#include <cstddef>
#include <cstdint>

#define SCALE_QK 0.17677669529663687f   // 32^-0.5

typedef __attribute__((ext_vector_type(8))) short bf16x8;
typedef __attribute__((ext_vector_type(4))) float f32x4;

// ---------------------------------------------------------------------------
// f32 -> bf16 conversion (weights)
// ---------------------------------------------------------------------------
__global__ __launch_bounds__(256) void convb_kernel(
    const float* __restrict__ src, __hip_bfloat16* __restrict__ dst, int n) {
  int i = blockIdx.x * 256 + threadIdx.x;
  if (i < n) dst[i] = __float2bfloat16(src[i]);
}

// ---------------------------------------------------------------------------
// LayerNorm + window partition -> bf16 rows
// ---------------------------------------------------------------------------
__global__ __launch_bounds__(256) void ln_part_kernel(
    const float* __restrict__ in, __hip_bfloat16* __restrict__ out,
    const float* __restrict__ gamma, const float* __restrict__ beta,
    int S, int b0) {
  int r = blockIdx.x;
  int n = r & 63;
  int tmp = r >> 6;
  int s = tmp % S;
  int b_ = b0 + tmp / S;
  int b  = b_ >> 6;
  int wh = (b_ >> 3) & 7;
  int ww = b_ & 7;
  int gh = wh * 8 + (n >> 3);
  int gw = ww * 8 + (n & 7);
  const float* src = in + (((size_t)(b * S + s) * 64 + gh) * 64 + gw) * 256;
  int c = threadIdx.x;
  float v = src[c];
  __shared__ float red[256];
  red[c] = v; __syncthreads();
  for (int off = 128; off > 0; off >>= 1) { if (c < off) red[c] += red[c + off]; __syncthreads(); }
  float mu = red[0] * (1.f / 256.f);
  __syncthreads();
  float dv = v - mu;
  red[c] = dv * dv; __syncthreads();
  for (int off = 128; off > 0; off >>= 1) { if (c < off) red[c] += red[c + off]; __syncthreads(); }
  float var = red[0] * (1.f / 256.f);
  out[(size_t)r * 256 + c] = __float2bfloat16(dv * rsqrtf(var + 1e-5f) * gamma[c] + beta[c]);
}

// Plain LayerNorm (f32 in) -> bf16 out
__global__ __launch_bounds__(256) void ln_plain_kernel(
    const float* __restrict__ in, __hip_bfloat16* __restrict__ out,
    const float* __restrict__ gamma, const float* __restrict__ beta) {
  int r = blockIdx.x;
  const float* src = in + (size_t)r * 256;
  int c = threadIdx.x;
  float v = src[c];
  __shared__ float red[256];
  red[c] = v; __syncthreads();
  for (int off = 128; off > 0; off >>= 1) { if (c < off) red[c] += red[c + off]; __syncthreads(); }
  float mu = red[0] * (1.f / 256.f);
  __syncthreads();
  float dv = v - mu;
  red[c] = dv * dv; __syncthreads();
  for (int off = 128; off > 0; off >>= 1) { if (c < off) red[c] += red[c + off]; __syncthreads(); }
  float var = red[0] * (1.f / 256.f);
  out[(size_t)r * 256 + c] = __float2bfloat16(dv * rsqrtf(var + 1e-5f) * gamma[c] + beta[c]);
}

// ---------------------------------------------------------------------------
// bf16 MFMA GEMM: C[M,N] = A[M,K](bf16) @ W[N,K](bf16)^T (+ bias)
// 128x128 tile, BK=64, 4 waves (2x2 of 64x64), 16x16x32 MFMA, XOR-swizzled LDS.
// flags: bit0 = gelu, bit1 = bf16 output. resid (f32) optional, f32-out only.
// ---------------------------------------------------------------------------
__global__ __launch_bounds__(256) void mgemm_kernel(
    const ushort* __restrict__ A, const ushort* __restrict__ W,
    const float* __restrict__ bias, const float* __restrict__ resid,
    void* __restrict__ Cp, int Mrows, int N, int K, int flags) {
  __shared__ ushort As[128 * 64];
  __shared__ ushort Bs[128 * 64];
  int tid = threadIdx.x;
  int lane = tid & 63, wid = tid >> 6;
  int wm = wid >> 1, wn = wid & 1;
  int row0 = blockIdx.y * 128, col0 = blockIdx.x * 128;
  int srow = tid >> 3;           // 0..31
  int slot = tid & 7;            // 16B slot within 128B row
  f32x4 acc[4][4];
  #pragma unroll
  for (int m = 0; m < 4; ++m)
    #pragma unroll
    for (int n = 0; n < 4; ++n) acc[m][n] = (f32x4){0.f, 0.f, 0.f, 0.f};

  for (int k0 = 0; k0 < K; k0 += 64) {
    #pragma unroll
    for (int i = 0; i < 4; ++i) {
      int r = i * 32 + srow;
      int gr = row0 + r; if (gr >= Mrows) gr = Mrows - 1;
      bf16x8 va = *(const bf16x8*)(A + (size_t)gr * K + k0 + slot * 8);
      int gc = col0 + r;
      bf16x8 vb = *(const bf16x8*)(W + (size_t)gc * K + k0 + slot * 8);
      int ldso = r * 64 + ((slot ^ (r & 7)) << 3);
      *(bf16x8*)(As + ldso) = va;
      *(bf16x8*)(Bs + ldso) = vb;
    }
    __syncthreads();
    #pragma unroll
    for (int ks = 0; ks < 2; ++ks) {
      bf16x8 af[4], bfr[4];
      int sgrp = ks * 4 + (lane >> 4);
      #pragma unroll
      for (int m = 0; m < 4; ++m) {
        int r = wm * 64 + m * 16 + (lane & 15);
        af[m] = *(const bf16x8*)(As + r * 64 + ((sgrp ^ (r & 7)) << 3));
      }
      #pragma unroll
      for (int n = 0; n < 4; ++n) {
        int r = wn * 64 + n * 16 + (lane & 15);
        bfr[n] = *(const bf16x8*)(Bs + r * 64 + ((sgrp ^ (r & 7)) << 3));
      }
      #pragma unroll
      for (int m = 0; m < 4; ++m)
        #pragma unroll
        for (int n = 0; n < 4; ++n)
          acc[m][n] = __builtin_amdgcn_mfma_f32_16x16x32_bf16(af[m], bfr[n], acc[m][n], 0, 0, 0);
    }
    __syncthreads();
  }

  float* Cf = (float*)Cp;
  __hip_bfloat16* Cb = (__hip_bfloat16*)Cp;
  #pragma unroll
  for (int m = 0; m < 4; ++m) {
    #pragma unroll
    for (int n = 0; n < 4; ++n) {
      int col = col0 + wn * 64 + n * 16 + (lane & 15);
      #pragma unroll
      for (int r = 0; r < 4; ++r) {
        int row = row0 + wm * 64 + m * 16 + (lane >> 4) * 4 + r;
        if (row >= Mrows) continue;
        float v = acc[m][n][r] + (bias ? bias[col] : 0.f);
        if (flags & 1) v = 0.5f * v * (1.f + erff(v * 0.70710678118654752f));
        if (resid) v += resid[(size_t)row * N + col];
        if (flags & 2) Cb[(size_t)row * N + col] = __float2bfloat16(v);
        else           Cf[(size_t)row * N + col] = v;
      }
    }
  }
}

// ---------------------------------------------------------------------------
// f32 GEMM (tiny 64-row pos_emb projections)
// ---------------------------------------------------------------------------
#define TBM 64
#define TBN 64
#define TBK 16
__global__ __launch_bounds__(256) void gemm_kernel(
    const float* __restrict__ A, const float* __restrict__ Wt,
    const float* __restrict__ bias, float* __restrict__ Cc,
    int Mrows, int Nout, int K) {
  __shared__ float Asl[TBK][TBM + 1];
  __shared__ float Wsl[TBK][TBN + 1];
  int tid = threadIdx.x;
  int tx = tid & 15, ty = tid >> 4;
  int row0 = blockIdx.y * TBM, col0 = blockIdx.x * TBN;
  float acc[4][4] = {};
  for (int k0 = 0; k0 < K; k0 += TBK) {
    #pragma unroll
    for (int t = 0; t < 4; ++t) {
      int idx = t * 256 + tid;
      int lm = idx >> 4, lk = idx & 15;
      int gr = row0 + lm;
      Asl[lk][lm] = (gr < Mrows) ? A[(size_t)gr * K + k0 + lk] : 0.f;
      int gc = col0 + lm;
      Wsl[lk][lm] = (gc < Nout) ? Wt[(size_t)gc * K + k0 + lk] : 0.f;
    }
    __syncthreads();
    #pragma unroll
    for (int kk = 0; kk < TBK; ++kk) {
      float a[4], b[4];
      #pragma unroll
      for (int i = 0; i < 4; ++i) a[i] = Asl[kk][ty * 4 + i];
      #pragma unroll
      for (int j = 0; j < 4; ++j) b[j] = Wsl[kk][tx * 4 + j];
      #pragma unroll
      for (int i = 0; i < 4; ++i)
        #pragma unroll
        for (int j = 0; j < 4; ++j)
          acc[i][j] = fmaf(a[i], b[j], acc[i][j]);
    }
    __syncthreads();
  }
  #pragma unroll
  for (int i = 0; i < 4; ++i) {
    int gr = row0 + ty * 4 + i;
    if (gr >= Mrows) continue;
    #pragma unroll
    for (int j = 0; j < 4; ++j) {
      int gc = col0 + tx * 4 + j;
      if (gc >= Nout) continue;
      Cc[(size_t)gr * Nout + gc] = acc[i][j] + bias[gc];
    }
  }
}

// ---------------------------------------------------------------------------
// Window attention: one block per (b_l, t, m, h), 64 threads. f32 in, bf16 out.
// ---------------------------------------------------------------------------
__global__ __launch_bounds__(64) void wattn_kernel(
    const float* __restrict__ qb, const float* __restrict__ kvp,
    const float* __restrict__ rpb_table, __hip_bfloat16* __restrict__ xw) {
  int idx = blockIdx.x;
  int h = idx & 7; idx >>= 3;
  int m = idx % 5; idx /= 5;
  int t = idx & 3; int b_l = idx >> 2;
  int n = threadIdx.x;
  __shared__ float ks[64][33];
  __shared__ float vs[64][33];
  const float* krow = kvp + (((size_t)(b_l * 5 + m) * 64 + n) * 512) + h * 32;
  #pragma unroll
  for (int d = 0; d < 32; ++d) { ks[n][d] = krow[d]; vs[n][d] = krow[256 + d]; }
  float qr[32];
  const float* qrow = qb + (((size_t)(b_l * 4 + t) * 64 + n) * 256) + h * 32;
  #pragma unroll
  for (int d = 0; d < 32; ++d) qr[d] = qrow[d] * SCALE_QK;
  __syncthreads();
  int i1 = n >> 3, j1 = n & 7;
  float mx = -1e30f;
  for (int j = 0; j < 64; ++j) {
    float a = 0.f;
    #pragma unroll
    for (int d = 0; d < 32; ++d) a = fmaf(qr[d], ks[j][d], a);
    a += rpb_table[((i1 - (j >> 3) + 7) * 15 + (j1 - (j & 7) + 7)) * 8 + h];
    mx = fmaxf(mx, a);
  }
  float l = 0.f;
  float acc[32];
  #pragma unroll
  for (int d = 0; d < 32; ++d) acc[d] = 0.f;
  for (int j = 0; j < 64; ++j) {
    float a = 0.f;
    #pragma unroll
    for (int d = 0; d < 32; ++d) a = fmaf(qr[d], ks[j][d], a);
    a += rpb_table[((i1 - (j >> 3) + 7) * 15 + (j1 - (j & 7) + 7)) * 8 + h];
    float p = __expf(a - mx);
    l += p;
    #pragma unroll
    for (int d = 0; d < 32; ++d) acc[d] = fmaf(p, vs[j][d], acc[d]);
  }
  float inv = 1.f / l;
  int f = m * 4 + t;
  int tp = f / 5, mp = f % 5;
  int np = h * 8 + (n >> 3);
  int cp = (n & 7) * 32;
  size_t base = ((((size_t)(b_l * 4 + tp) * 5 + mp) * 64 + np) * 256) + cp;
  #pragma unroll
  for (int d = 0; d < 32; ++d) xw[base + d] = __float2bfloat16(acc[d] * inv);
}

// ---------------------------------------------------------------------------
// avg3: avgq(bf16) = mean_m xw + pos ; pka/pva(f32) = mean_m PK/PV
// ---------------------------------------------------------------------------
__global__ __launch_bounds__(256) void avg3_kernel(
    const __hip_bfloat16* __restrict__ xw, const float* __restrict__ pk,
    const float* __restrict__ pv, const float* __restrict__ pos_emb,
    __hip_bfloat16* __restrict__ avgq, float* __restrict__ pka,
    float* __restrict__ pva) {
  int gid = blockIdx.x * 256 + threadIdx.x;
  int c = gid & 255;
  int rn = gid >> 8;
  int n = rn & 63;
  int bp = rn >> 6;
  size_t base = ((size_t)bp * 320 + n) * 256 + c;
  const size_t stride = 64 * 256;
  float sq = 0.f, sk = 0.f, sv = 0.f;
  #pragma unroll
  for (int m = 0; m < 5; ++m) {
    sq += __bfloat162float(xw[base + m * stride]);
    sk += pk[base + m * stride];
    sv += pv[base + m * stride];
  }
  avgq[(size_t)rn * 256 + c] = __float2bfloat16(sq * 0.2f + pos_emb[n * 256 + c]);
  pka[(size_t)rn * 256 + c] = sk * 0.2f;
  pva[(size_t)rn * 256 + c] = sv * 0.2f;
}

// ---------------------------------------------------------------------------
// Pool attention v2: one block per (bp_l, h), 256 threads = 4 waves.
// Each wave owns a 16-key strip of every 64-key chunk; split-softmax merge.
// K/V staged as float4 in LDS (8x ds_read_b128 per key), pos_pk/pos_pv
// preloaded to registers (constant across the 6 chunks).
// ---------------------------------------------------------------------------
__global__ __launch_bounds__(256) void pattn_kernel(
    const float* __restrict__ pq, const float* __restrict__ pk,
    const float* __restrict__ pv, const float* __restrict__ pka,
    const float* __restrict__ pva, const float* __restrict__ pos_pk,
    const float* __restrict__ pos_pv, __hip_bfloat16* __restrict__ o) {
  int h = blockIdx.x & 7;
  int bp = blockIdx.x >> 3;
  int tid = threadIdx.x;
  int lane = tid & 63;        // query index
  int w = tid >> 6;           // wave id -> key strip [w*16, w*16+16)
  __shared__ float4 ks4[64][9];
  __shared__ float4 vs4[64][9];
  __shared__ float sm[4][64];
  __shared__ float sl[4][64];
  __shared__ float sacc[4][64][32];

  // staging assignment: thread stages row sr, d-slice [dg*8, dg*8+8)
  int sr = tid >> 2, dg = tid & 3;
  const float* ppkp = pos_pk + sr * 256 + h * 32 + dg * 8;
  const float* ppvp = pos_pv + sr * 256 + h * 32 + dg * 8;
  float4 ppk0 = *(const float4*)(ppkp);
  float4 ppk1 = *(const float4*)(ppkp + 4);
  float4 ppv0 = *(const float4*)(ppvp);
  float4 ppv1 = *(const float4*)(ppvp + 4);

  float qr[32];
  {
    const float* qrow = pq + (((size_t)bp * 64 + lane) * 256) + h * 32;
    #pragma unroll
    for (int i = 0; i < 8; ++i) {
      float4 qv = *(const float4*)(qrow + i * 4);
      qr[i*4+0] = qv.x * SCALE_QK; qr[i*4+1] = qv.y * SCALE_QK;
      qr[i*4+2] = qv.z * SCALE_QK; qr[i*4+3] = qv.w * SCALE_QK;
    }
  }

  float mx = -1e30f, l = 0.f;
  float acc[32];
  #pragma unroll
  for (int d = 0; d < 32; ++d) acc[d] = 0.f;

  for (int mm = 0; mm < 6; ++mm) {
    const float* kr;
    const float* vr;
    if (mm == 0) {
      kr = pka + (((size_t)bp * 64 + sr) * 256) + h * 32 + dg * 8;
      vr = pva + (((size_t)bp * 64 + sr) * 256) + h * 32 + dg * 8;
    } else {
      kr = pk + (((size_t)(bp * 5 + mm - 1) * 64 + sr) * 256) + h * 32 + dg * 8;
      vr = pv + (((size_t)(bp * 5 + mm - 1) * 64 + sr) * 256) + h * 32 + dg * 8;
    }
    __syncthreads();   // previous chunk fully consumed before overwrite
    {
      float4 a0 = *(const float4*)(kr);
      float4 a1 = *(const float4*)(kr + 4);
      float4 b0 = *(const float4*)(vr);
      float4 b1 = *(const float4*)(vr + 4);
      ks4[sr][dg*2]   = make_float4(a0.x+ppk0.x, a0.y+ppk0.y, a0.z+ppk0.z, a0.w+ppk0.w);
      ks4[sr][dg*2+1] = make_float4(a1.x+ppk1.x, a1.y+ppk1.y, a1.z+ppk1.z, a1.w+ppk1.w);
      vs4[sr][dg*2]   = make_float4(b0.x+ppv0.x, b0.y+ppv0.y, b0.z+ppv0.z, b0.w+ppv0.w);
      vs4[sr][dg*2+1] = make_float4(b1.x+ppv1.x, b1.y+ppv1.y, b1.z+ppv1.z, b1.w+ppv1.w);
    }
    __syncthreads();

    // pass 1: scores for this wave's 16-key strip, kept in registers
    float s[16];
    float cmx = mx;
    #pragma unroll
    for (int jj = 0; jj < 16; ++jj) {
      int j = w * 16 + jj;
      float a = 0.f;
      #pragma unroll
      for (int i = 0; i < 8; ++i) {
        float4 kk = ks4[j][i];
        a = fmaf(qr[i*4+0], kk.x, a);
        a = fmaf(qr[i*4+1], kk.y, a);
        a = fmaf(qr[i*4+2], kk.z, a);
        a = fmaf(qr[i*4+3], kk.w, a);
      }
      s[jj] = a;
      cmx = fmaxf(cmx, a);
    }
    float scale = __expf(mx - cmx);
    l *= scale;
    #pragma unroll
    for (int d = 0; d < 32; ++d) acc[d] *= scale;
    // pass 2: exp + PV accumulate
    #pragma unroll
    for (int jj = 0; jj < 16; ++jj) {
      int j = w * 16 + jj;
      float p = __expf(s[jj] - cmx);
      l += p;
      #pragma unroll
      for (int i = 0; i < 8; ++i) {
        float4 vv = vs4[j][i];
        acc[i*4+0] = fmaf(p, vv.x, acc[i*4+0]);
        acc[i*4+1] = fmaf(p, vv.y, acc[i*4+1]);
        acc[i*4+2] = fmaf(p, vv.z, acc[i*4+2]);
        acc[i*4+3] = fmaf(p, vv.w, acc[i*4+3]);
      }
    }
    mx = cmx;
  }

  // split-softmax merge across the 4 waves
  sm[w][lane] = mx;
  sl[w][lane] = l;
  #pragma unroll
  for (int d = 0; d < 32; ++d) sacc[w][lane][d] = acc[d];
  __syncthreads();

  float M = fmaxf(fmaxf(sm[0][lane], sm[1][lane]), fmaxf(sm[2][lane], sm[3][lane]));
  float e0 = __expf(sm[0][lane] - M);
  float e1 = __expf(sm[1][lane] - M);
  float e2 = __expf(sm[2][lane] - M);
  float e3 = __expf(sm[3][lane] - M);
  float L = sl[0][lane]*e0 + sl[1][lane]*e1 + sl[2][lane]*e2 + sl[3][lane]*e3;
  float inv = 1.f / L;
  size_t base = (((size_t)bp * 64 + lane) * 256) + h * 32 + w * 8;
  #pragma unroll
  for (int dd = 0; dd < 8; ++dd) {
    int d = w * 8 + dd;
    float sv = sacc[0][lane][d]*e0 + sacc[1][lane][d]*e1
             + sacc[2][lane][d]*e2 + sacc[3][lane][d]*e3;
    o[base + dd] = __float2bfloat16(sv * inv);
  }
}

// ---------------------------------------------------------------------------
// scatter: out[pixel] = x[pixel] + prj[row]  (window reverse + residual)
// ---------------------------------------------------------------------------
__global__ __launch_bounds__(256) void scatter_kernel(
    const float* __restrict__ x, const float* __restrict__ prj,
    float* __restrict__ out, int b0) {
  int gid = blockIdx.x * 256 + threadIdx.x;
  int c = gid & 255;
  int r = gid >> 8;
  int n = r & 63;
  int t = (r >> 6) & 3;
  int b_l = r >> 8;
  int b_ = b0 + b_l;
  int b = b_ >> 6, wh = (b_ >> 3) & 7, ww = b_ & 7;
  int gh = wh * 8 + (n >> 3), gw = ww * 8 + (n & 7);
  size_t pix = (((size_t)(b * 4 + t) * 64 + gh) * 64 + gw) * 256 + c;
  out[pix] = x[pix] + prj[(size_t)r * 256 + c];
}

// ---------------------------------------------------------------------------
// Launch
// ---------------------------------------------------------------------------
extern "C" void kernel_launch(void* const* d_in, const int* in_sizes, int n_in,
                              void* d_out, int out_size, void* d_ws, size_t ws_size,
                              hipStream_t stream) {
  const float* x       = (const float*)d_in[0];
  const float* kv      = (const float*)d_in[1];
  const float* nq_g    = (const float*)d_in[3];
  const float* nq_b    = (const float*)d_in[4];
  const float* nk_g    = (const float*)d_in[5];
  const float* nk_b    = (const float*)d_in[6];
  const float* q_w     = (const float*)d_in[7];
  const float* q_b     = (const float*)d_in[8];
  const float* kv_w    = (const float*)d_in[9];
  const float* kv_b    = (const float*)d_in[10];
  const float* rpb     = (const float*)d_in[11];
  const float* pos_emb = (const float*)d_in[12];
  const float* pq_w    = (const float*)d_in[13];
  const float* pq_b    = (const float*)d_in[14];
  const float* pk_w    = (const float*)d_in[15];
  const float* pk_b    = (const float*)d_in[16];
  const float* pv_w    = (const float*)d_in[17];
  const float* pv_b    = (const float*)d_in[18];
  const float* po_w    = (const float*)d_in[19];
  const float* po_b    = (const float*)d_in[20];
  const float* proj_w  = (const float*)d_in[21];
  const float* proj_b  = (const float*)d_in[22];
  const float* n2_g    = (const float*)d_in[23];
  const float* n2_b    = (const float*)d_in[24];
  const float* mlp_w1  = (const float*)d_in[25];
  const float* mlp_b1  = (const float*)d_in[26];
  const float* mlp_w2  = (const float*)d_in[27];
  const float* mlp_b2  = (const float*)d_in[28];
  float* out = (float*)d_out;
  float* ws = (float*)d_ws;

  size_t wsF = ws_size / sizeof(float);
  float* pospk = ws;
  float* pospv = ws + 16384;
  __hip_bfloat16* wq_b    = (__hip_bfloat16*)(ws + 32768);
  __hip_bfloat16* wkv_b   = (__hip_bfloat16*)(ws + 65536);
  __hip_bfloat16* wpq_b   = (__hip_bfloat16*)(ws + 131072);
  __hip_bfloat16* wpk_b   = (__hip_bfloat16*)(ws + 163840);
  __hip_bfloat16* wpv_b   = (__hip_bfloat16*)(ws + 196608);
  __hip_bfloat16* wpo_b   = (__hip_bfloat16*)(ws + 229376);
  __hip_bfloat16* wproj_b = (__hip_bfloat16*)(ws + 262144);
  __hip_bfloat16* wm1_b   = (__hip_bfloat16*)(ws + 294912);
  __hip_bfloat16* wm2_b   = (__hip_bfloat16*)(ws + 425984);
  const size_t FIXED = 557056;

  int CH = 0;
  const int cands[7] = {64, 32, 16, 8, 4, 2, 1};
  for (int i = 0; i < 7; ++i) {
    size_t need = FIXED + (size_t)1179648 * cands[i];
    if (need <= wsF) { CH = cands[i]; break; }
  }
  if (CH == 0) return;
  size_t CHs = (size_t)CH;
  float* cb = ws + FIXED;

  __hip_bfloat16* qw_b  = (__hip_bfloat16*)cb;
  __hip_bfloat16* kvw_b = (__hip_bfloat16*)(cb + 32768 * CHs);
  float* qb2 = cb + 73728 * CHs;
  float* kvp = cb + 139264 * CHs;
  float* PK  = cb;
  float* PV  = cb + 327680 * CHs;
  __hip_bfloat16* xw_b  = (__hip_bfloat16*)(cb + 655360 * CHs);
  __hip_bfloat16* AVG_b = (__hip_bfloat16*)(cb + 819200 * CHs);
  float* PQ  = cb + 851968 * CHs;
  float* PKA = cb + 917504 * CHs;
  float* PVA = cb + 983040 * CHs;
  __hip_bfloat16* OC_b = (__hip_bfloat16*)(cb + 1048576 * CHs);
  __hip_bfloat16* PG_b = (__hip_bfloat16*)(cb + 1081344 * CHs);
  float* PRJ = cb + 1114112 * CHs;

  gemm_kernel<<<dim3(4, 1), 256, 0, stream>>>(pos_emb, pk_w, pk_b, pospk, 64, 256, 256);
  gemm_kernel<<<dim3(4, 1), 256, 0, stream>>>(pos_emb, pv_w, pv_b, pospv, 64, 256, 256);
  convb_kernel<<<256,  256, 0, stream>>>(q_w,    wq_b,    65536);
  convb_kernel<<<512,  256, 0, stream>>>(kv_w,   wkv_b,   131072);
  convb_kernel<<<256,  256, 0, stream>>>(pq_w,   wpq_b,   65536);
  convb_kernel<<<256,  256, 0, stream>>>(pk_w,   wpk_b,   65536);
  convb_kernel<<<256,  256, 0, stream>>>(pv_w,   wpv_b,   65536);
  convb_kernel<<<256,  256, 0, stream>>>(po_w,   wpo_b,   65536);
  convb_kernel<<<256,  256, 0, stream>>>(proj_w, wproj_b, 65536);
  convb_kernel<<<1024, 256, 0, stream>>>(mlp_w1, wm1_b,   262144);
  convb_kernel<<<1024, 256, 0, stream>>>(mlp_w2, wm2_b,   262144);

  for (int c0 = 0; c0 < 128; c0 += CH) {
    int rowsQ  = CH * 256;
    int rowsKV = CH * 320;
    int rowsXW = CH * 1280;
    int bpC    = CH * 4;
    int rowsP  = bpC * 64;
    ln_part_kernel<<<rowsQ, 256, 0, stream>>>(x, qw_b, nq_g, nq_b, 4, c0);
    ln_part_kernel<<<rowsKV, 256, 0, stream>>>(kv, kvw_b, nk_g, nk_b, 5, c0);
    mgemm_kernel<<<dim3(2, rowsQ / 128), 256, 0, stream>>>(
        (const ushort*)qw_b, (const ushort*)wq_b, q_b, nullptr, qb2, rowsQ, 256, 256, 0);
    mgemm_kernel<<<dim3(4, (rowsKV + 127) / 128), 256, 0, stream>>>(
        (const ushort*)kvw_b, (const ushort*)wkv_b, kv_b, nullptr, kvp, rowsKV, 512, 256, 0);
    wattn_kernel<<<CH * 160, 64, 0, stream>>>(qb2, kvp, rpb, xw_b);
    mgemm_kernel<<<dim3(2, rowsXW / 128), 256, 0, stream>>>(
        (const ushort*)xw_b, (const ushort*)wpk_b, nullptr, nullptr, PK, rowsXW, 256, 256, 0);
    mgemm_kernel<<<dim3(2, rowsXW / 128), 256, 0, stream>>>(
        (const ushort*)xw_b, (const ushort*)wpv_b, nullptr, nullptr, PV, rowsXW, 256, 256, 0);
    avg3_kernel<<<rowsP, 256, 0, stream>>>(xw_b, PK, PV, pos_emb, AVG_b, PKA, PVA);
    mgemm_kernel<<<dim3(2, rowsP / 128), 256, 0, stream>>>(
        (const ushort*)AVG_b, (const ushort*)wpq_b, pq_b, nullptr, PQ, rowsP, 256, 256, 0);
    pattn_kernel<<<bpC * 8, 256, 0, stream>>>(PQ, PK, PV, PKA, PVA, pospk, pospv, OC_b);
    mgemm_kernel<<<dim3(2, rowsP / 128), 256, 0, stream>>>(
        (const ushort*)OC_b, (const ushort*)wpo_b, po_b, nullptr, PG_b, rowsP, 256, 256, 3);
    mgemm_kernel<<<dim3(2, rowsP / 128), 256, 0, stream>>>(
        (const ushort*)PG_b, (const ushort*)wproj_b, proj_b, nullptr, PRJ, rowsP, 256, 256, 0);
    scatter_kernel<<<rowsP, 256, 0, stream>>>(x, PRJ, out, c0);
  }

  int R = 32768;
  while ((size_t)R * 640 > (size_t)1179648 * CHs && R > 128) R >>= 1;
  __hip_bfloat16* ln2c = (__hip_bfloat16*)cb;
  __hip_bfloat16* h1c  = (__hip_bfloat16*)(cb + 128 * (size_t)R);
  for (int r0 = 0; r0 < 32768; r0 += R) {
    ln_plain_kernel<<<R, 256, 0, stream>>>(out + (size_t)r0 * 256, ln2c, n2_g, n2_b);
    mgemm_kernel<<<dim3(8, R / 128), 256, 0, stream>>>(
        (const ushort*)ln2c, (const ushort*)wm1_b, mlp_b1, nullptr, h1c, R, 1024, 256, 3);
    mgemm_kernel<<<dim3(2, R / 128), 256, 0, stream>>>(
        (const ushort*)h1c, (const ushort*)wm2_b, mlp_b2, out + (size_t)r0 * 256,
        out + (size_t)r0 * 256, R, 256, 1024, 0);
  }
}

// Round 8
// 2172.597 us; speedup vs baseline: 2.4151x; 1.0509x over previous
//
#include <hip/hip_runtime.h>
#include <hip/hip_bf16.h>
#include <cstddef>
#include <cstdint>

#define SCALE_QK 0.17677669529663687f   // 32^-0.5

typedef __attribute__((ext_vector_type(8))) short bf16x8;
typedef __attribute__((ext_vector_type(4))) float f32x4;

// ---------------------------------------------------------------------------
// f32 -> bf16 conversion (weights)
// ---------------------------------------------------------------------------
__global__ __launch_bounds__(256) void convb_kernel(
    const float* __restrict__ src, __hip_bfloat16* __restrict__ dst, int n) {
  int i = blockIdx.x * 256 + threadIdx.x;
  if (i < n) dst[i] = __float2bfloat16(src[i]);
}

// ---------------------------------------------------------------------------
// LayerNorm + window partition -> bf16 rows
// ---------------------------------------------------------------------------
__global__ __launch_bounds__(256) void ln_part_kernel(
    const float* __restrict__ in, __hip_bfloat16* __restrict__ out,
    const float* __restrict__ gamma, const float* __restrict__ beta,
    int S, int b0) {
  int r = blockIdx.x;
  int n = r & 63;
  int tmp = r >> 6;
  int s = tmp % S;
  int b_ = b0 + tmp / S;
  int b  = b_ >> 6;
  int wh = (b_ >> 3) & 7;
  int ww = b_ & 7;
  int gh = wh * 8 + (n >> 3);
  int gw = ww * 8 + (n & 7);
  const float* src = in + (((size_t)(b * S + s) * 64 + gh) * 64 + gw) * 256;
  int c = threadIdx.x;
  float v = src[c];
  __shared__ float red[256];
  red[c] = v; __syncthreads();
  for (int off = 128; off > 0; off >>= 1) { if (c < off) red[c] += red[c + off]; __syncthreads(); }
  float mu = red[0] * (1.f / 256.f);
  __syncthreads();
  float dv = v - mu;
  red[c] = dv * dv; __syncthreads();
  for (int off = 128; off > 0; off >>= 1) { if (c < off) red[c] += red[c + off]; __syncthreads(); }
  float var = red[0] * (1.f / 256.f);
  out[(size_t)r * 256 + c] = __float2bfloat16(dv * rsqrtf(var + 1e-5f) * gamma[c] + beta[c]);
}

// Plain LayerNorm (f32 in) -> bf16 out
__global__ __launch_bounds__(256) void ln_plain_kernel(
    const float* __restrict__ in, __hip_bfloat16* __restrict__ out,
    const float* __restrict__ gamma, const float* __restrict__ beta) {
  int r = blockIdx.x;
  const float* src = in + (size_t)r * 256;
  int c = threadIdx.x;
  float v = src[c];
  __shared__ float red[256];
  red[c] = v; __syncthreads();
  for (int off = 128; off > 0; off >>= 1) { if (c < off) red[c] += red[c + off]; __syncthreads(); }
  float mu = red[0] * (1.f / 256.f);
  __syncthreads();
  float dv = v - mu;
  red[c] = dv * dv; __syncthreads();
  for (int off = 128; off > 0; off >>= 1) { if (c < off) red[c] += red[c + off]; __syncthreads(); }
  float var = red[0] * (1.f / 256.f);
  out[(size_t)r * 256 + c] = __float2bfloat16(dv * rsqrtf(var + 1e-5f) * gamma[c] + beta[c]);
}

// ---------------------------------------------------------------------------
// bf16 MFMA GEMM: C[M,N] = A[M,K](bf16) @ W[N,K](bf16)^T (+ bias)
// 128x128 tile, BK=64, 4 waves (2x2 of 64x64), 16x16x32 MFMA, XOR-swizzled LDS.
// flags: bit0 = gelu, bit1 = bf16 output. resid (f32) optional, f32-out only.
// ---------------------------------------------------------------------------
__global__ __launch_bounds__(256) void mgemm_kernel(
    const ushort* __restrict__ A, const ushort* __restrict__ W,
    const float* __restrict__ bias, const float* __restrict__ resid,
    void* __restrict__ Cp, int Mrows, int N, int K, int flags) {
  __shared__ ushort As[128 * 64];
  __shared__ ushort Bs[128 * 64];
  int tid = threadIdx.x;
  int lane = tid & 63, wid = tid >> 6;
  int wm = wid >> 1, wn = wid & 1;
  int row0 = blockIdx.y * 128, col0 = blockIdx.x * 128;
  int srow = tid >> 3;           // 0..31
  int slot = tid & 7;            // 16B slot within 128B row
  f32x4 acc[4][4];
  #pragma unroll
  for (int m = 0; m < 4; ++m)
    #pragma unroll
    for (int n = 0; n < 4; ++n) acc[m][n] = (f32x4){0.f, 0.f, 0.f, 0.f};

  for (int k0 = 0; k0 < K; k0 += 64) {
    #pragma unroll
    for (int i = 0; i < 4; ++i) {
      int r = i * 32 + srow;
      int gr = row0 + r; if (gr >= Mrows) gr = Mrows - 1;
      bf16x8 va = *(const bf16x8*)(A + (size_t)gr * K + k0 + slot * 8);
      int gc = col0 + r;
      bf16x8 vb = *(const bf16x8*)(W + (size_t)gc * K + k0 + slot * 8);
      int ldso = r * 64 + ((slot ^ (r & 7)) << 3);
      *(bf16x8*)(As + ldso) = va;
      *(bf16x8*)(Bs + ldso) = vb;
    }
    __syncthreads();
    #pragma unroll
    for (int ks = 0; ks < 2; ++ks) {
      bf16x8 af[4], bfr[4];
      int sgrp = ks * 4 + (lane >> 4);
      #pragma unroll
      for (int m = 0; m < 4; ++m) {
        int r = wm * 64 + m * 16 + (lane & 15);
        af[m] = *(const bf16x8*)(As + r * 64 + ((sgrp ^ (r & 7)) << 3));
      }
      #pragma unroll
      for (int n = 0; n < 4; ++n) {
        int r = wn * 64 + n * 16 + (lane & 15);
        bfr[n] = *(const bf16x8*)(Bs + r * 64 + ((sgrp ^ (r & 7)) << 3));
      }
      #pragma unroll
      for (int m = 0; m < 4; ++m)
        #pragma unroll
        for (int n = 0; n < 4; ++n)
          acc[m][n] = __builtin_amdgcn_mfma_f32_16x16x32_bf16(af[m], bfr[n], acc[m][n], 0, 0, 0);
    }
    __syncthreads();
  }

  float* Cf = (float*)Cp;
  __hip_bfloat16* Cb = (__hip_bfloat16*)Cp;
  #pragma unroll
  for (int m = 0; m < 4; ++m) {
    #pragma unroll
    for (int n = 0; n < 4; ++n) {
      int col = col0 + wn * 64 + n * 16 + (lane & 15);
      #pragma unroll
      for (int r = 0; r < 4; ++r) {
        int row = row0 + wm * 64 + m * 16 + (lane >> 4) * 4 + r;
        if (row >= Mrows) continue;
        float v = acc[m][n][r] + (bias ? bias[col] : 0.f);
        if (flags & 1) v = 0.5f * v * (1.f + erff(v * 0.70710678118654752f));
        if (resid) v += resid[(size_t)row * N + col];
        if (flags & 2) Cb[(size_t)row * N + col] = __float2bfloat16(v);
        else           Cf[(size_t)row * N + col] = v;
      }
    }
  }
}

// ---------------------------------------------------------------------------
// f32 GEMM (tiny 64-row pos_emb projections)
// ---------------------------------------------------------------------------
#define TBM 64
#define TBN 64
#define TBK 16
__global__ __launch_bounds__(256) void gemm_kernel(
    const float* __restrict__ A, const float* __restrict__ Wt,
    const float* __restrict__ bias, float* __restrict__ Cc,
    int Mrows, int Nout, int K) {
  __shared__ float Asl[TBK][TBM + 1];
  __shared__ float Wsl[TBK][TBN + 1];
  int tid = threadIdx.x;
  int tx = tid & 15, ty = tid >> 4;
  int row0 = blockIdx.y * TBM, col0 = blockIdx.x * TBN;
  float acc[4][4] = {};
  for (int k0 = 0; k0 < K; k0 += TBK) {
    #pragma unroll
    for (int t = 0; t < 4; ++t) {
      int idx = t * 256 + tid;
      int lm = idx >> 4, lk = idx & 15;
      int gr = row0 + lm;
      Asl[lk][lm] = (gr < Mrows) ? A[(size_t)gr * K + k0 + lk] : 0.f;
      int gc = col0 + lm;
      Wsl[lk][lm] = (gc < Nout) ? Wt[(size_t)gc * K + k0 + lk] : 0.f;
    }
    __syncthreads();
    #pragma unroll
    for (int kk = 0; kk < TBK; ++kk) {
      float a[4], b[4];
      #pragma unroll
      for (int i = 0; i < 4; ++i) a[i] = Asl[kk][ty * 4 + i];
      #pragma unroll
      for (int j = 0; j < 4; ++j) b[j] = Wsl[kk][tx * 4 + j];
      #pragma unroll
      for (int i = 0; i < 4; ++i)
        #pragma unroll
        for (int j = 0; j < 4; ++j)
          acc[i][j] = fmaf(a[i], b[j], acc[i][j]);
    }
    __syncthreads();
  }
  #pragma unroll
  for (int i = 0; i < 4; ++i) {
    int gr = row0 + ty * 4 + i;
    if (gr >= Mrows) continue;
    #pragma unroll
    for (int j = 0; j < 4; ++j) {
      int gc = col0 + tx * 4 + j;
      if (gc >= Nout) continue;
      Cc[(size_t)gr * Nout + gc] = acc[i][j] + bias[gc];
    }
  }
}

// ---------------------------------------------------------------------------
// Window attention v2: one block per (b_l, m, h), 256 threads = 4 waves.
// Wave w handles t=w (64 queries, one per lane). K/V staged once as float4
// (shared across the 4 t's); rpb bias tile staged once into LDS.
// Single QK pass with scores in registers, then exp+PV pass. bf16 out.
// ---------------------------------------------------------------------------
__global__ __launch_bounds__(256) void wattn_kernel(
    const float* __restrict__ qb, const float* __restrict__ kvp,
    const float* __restrict__ rpb_table, __hip_bfloat16* __restrict__ xw) {
  int idx = blockIdx.x;
  int h = idx & 7; idx >>= 3;
  int m = idx % 5;
  int b_l = idx / 5;
  int tid = threadIdx.x;
  int n = tid & 63;          // query index within window
  int w = tid >> 6;          // wave id = t

  __shared__ float4 ks4[64][9];
  __shared__ float4 vs4[64][9];
  __shared__ float rpbs[64][65];

  // stage K/V: thread stages row sr, d-slice [dg*8, dg*8+8)
  {
    int sr = tid >> 2, dg = tid & 3;
    const float* base = kvp + (((size_t)(b_l * 5 + m) * 64 + sr) * 512) + h * 32 + dg * 8;
    float4 k0 = *(const float4*)(base);
    float4 k1 = *(const float4*)(base + 4);
    float4 v0 = *(const float4*)(base + 256);
    float4 v1 = *(const float4*)(base + 260);
    ks4[sr][dg * 2]     = k0;
    ks4[sr][dg * 2 + 1] = k1;
    vs4[sr][dg * 2]     = v0;
    vs4[sr][dg * 2 + 1] = v1;
  }
  // stage rpb bias tile for head h: rpbs[n][j]
  for (int e = tid; e < 4096; e += 256) {
    int nn = e >> 6, jj = e & 63;
    int i1 = nn >> 3, j1 = nn & 7, i2 = jj >> 3, j2 = jj & 7;
    rpbs[nn][jj] = rpb_table[((i1 - i2 + 7) * 15 + (j1 - j2 + 7)) * 8 + h];
  }

  // load query row (t=w, query n)
  float qr[32];
  {
    const float* qrow = qb + (((size_t)(b_l * 4 + w) * 64 + n) * 256) + h * 32;
    #pragma unroll
    for (int i = 0; i < 8; ++i) {
      float4 qv = *(const float4*)(qrow + i * 4);
      qr[i*4+0] = qv.x * SCALE_QK; qr[i*4+1] = qv.y * SCALE_QK;
      qr[i*4+2] = qv.z * SCALE_QK; qr[i*4+3] = qv.w * SCALE_QK;
    }
  }
  __syncthreads();

  // pass 1: scores (single QK pass, scores kept in registers)
  float s[64];
  float mx = -1e30f;
  #pragma unroll
  for (int j = 0; j < 64; ++j) {
    float a = 0.f;
    #pragma unroll
    for (int i = 0; i < 8; ++i) {
      float4 kk = ks4[j][i];
      a = fmaf(qr[i*4+0], kk.x, a);
      a = fmaf(qr[i*4+1], kk.y, a);
      a = fmaf(qr[i*4+2], kk.z, a);
      a = fmaf(qr[i*4+3], kk.w, a);
    }
    a += rpbs[n][j];
    s[j] = a;
    mx = fmaxf(mx, a);
  }

  // pass 2: exp + PV accumulate
  float l = 0.f;
  float acc[32];
  #pragma unroll
  for (int d = 0; d < 32; ++d) acc[d] = 0.f;
  #pragma unroll
  for (int j = 0; j < 64; ++j) {
    float p = __expf(s[j] - mx);
    l += p;
    #pragma unroll
    for (int i = 0; i < 8; ++i) {
      float4 vv = vs4[j][i];
      acc[i*4+0] = fmaf(p, vv.x, acc[i*4+0]);
      acc[i*4+1] = fmaf(p, vv.y, acc[i*4+1]);
      acc[i*4+2] = fmaf(p, vv.z, acc[i*4+2]);
      acc[i*4+3] = fmaf(p, vv.w, acc[i*4+3]);
    }
  }
  float inv = 1.f / l;

  // scramble: f=m*4+t -> tp=f/5, mp=f%5 ; np=h*8+n/8 ; cp=(n%8)*32+d
  int f = m * 4 + w;
  int tp = f / 5, mp = f % 5;
  int np = h * 8 + (n >> 3);
  int cp = (n & 7) * 32;
  size_t base = ((((size_t)(b_l * 4 + tp) * 5 + mp) * 64 + np) * 256) + cp;
  #pragma unroll
  for (int d = 0; d < 32; ++d) xw[base + d] = __float2bfloat16(acc[d] * inv);
}

// ---------------------------------------------------------------------------
// avg3: avgq(bf16) = mean_m xw + pos ; pka/pva(f32) = mean_m PK/PV
// ---------------------------------------------------------------------------
__global__ __launch_bounds__(256) void avg3_kernel(
    const __hip_bfloat16* __restrict__ xw, const float* __restrict__ pk,
    const float* __restrict__ pv, const float* __restrict__ pos_emb,
    __hip_bfloat16* __restrict__ avgq, float* __restrict__ pka,
    float* __restrict__ pva) {
  int gid = blockIdx.x * 256 + threadIdx.x;
  int c = gid & 255;
  int rn = gid >> 8;
  int n = rn & 63;
  int bp = rn >> 6;
  size_t base = ((size_t)bp * 320 + n) * 256 + c;
  const size_t stride = 64 * 256;
  float sq = 0.f, sk = 0.f, sv = 0.f;
  #pragma unroll
  for (int m = 0; m < 5; ++m) {
    sq += __bfloat162float(xw[base + m * stride]);
    sk += pk[base + m * stride];
    sv += pv[base + m * stride];
  }
  avgq[(size_t)rn * 256 + c] = __float2bfloat16(sq * 0.2f + pos_emb[n * 256 + c]);
  pka[(size_t)rn * 256 + c] = sk * 0.2f;
  pva[(size_t)rn * 256 + c] = sv * 0.2f;
}

// ---------------------------------------------------------------------------
// Pool attention v2: one block per (bp_l, h), 256 threads = 4 waves.
// ---------------------------------------------------------------------------
__global__ __launch_bounds__(256) void pattn_kernel(
    const float* __restrict__ pq, const float* __restrict__ pk,
    const float* __restrict__ pv, const float* __restrict__ pka,
    const float* __restrict__ pva, const float* __restrict__ pos_pk,
    const float* __restrict__ pos_pv, __hip_bfloat16* __restrict__ o) {
  int h = blockIdx.x & 7;
  int bp = blockIdx.x >> 3;
  int tid = threadIdx.x;
  int lane = tid & 63;        // query index
  int w = tid >> 6;           // wave id -> key strip [w*16, w*16+16)
  __shared__ float4 ks4[64][9];
  __shared__ float4 vs4[64][9];
  __shared__ float sm[4][64];
  __shared__ float sl[4][64];
  __shared__ float sacc[4][64][32];

  int sr = tid >> 2, dg = tid & 3;
  const float* ppkp = pos_pk + sr * 256 + h * 32 + dg * 8;
  const float* ppvp = pos_pv + sr * 256 + h * 32 + dg * 8;
  float4 ppk0 = *(const float4*)(ppkp);
  float4 ppk1 = *(const float4*)(ppkp + 4);
  float4 ppv0 = *(const float4*)(ppvp);
  float4 ppv1 = *(const float4*)(ppvp + 4);

  float qr[32];
  {
    const float* qrow = pq + (((size_t)bp * 64 + lane) * 256) + h * 32;
    #pragma unroll
    for (int i = 0; i < 8; ++i) {
      float4 qv = *(const float4*)(qrow + i * 4);
      qr[i*4+0] = qv.x * SCALE_QK; qr[i*4+1] = qv.y * SCALE_QK;
      qr[i*4+2] = qv.z * SCALE_QK; qr[i*4+3] = qv.w * SCALE_QK;
    }
  }

  float mx = -1e30f, l = 0.f;
  float acc[32];
  #pragma unroll
  for (int d = 0; d < 32; ++d) acc[d] = 0.f;

  for (int mm = 0; mm < 6; ++mm) {
    const float* kr;
    const float* vr;
    if (mm == 0) {
      kr = pka + (((size_t)bp * 64 + sr) * 256) + h * 32 + dg * 8;
      vr = pva + (((size_t)bp * 64 + sr) * 256) + h * 32 + dg * 8;
    } else {
      kr = pk + (((size_t)(bp * 5 + mm - 1) * 64 + sr) * 256) + h * 32 + dg * 8;
      vr = pv + (((size_t)(bp * 5 + mm - 1) * 64 + sr) * 256) + h * 32 + dg * 8;
    }
    __syncthreads();
    {
      float4 a0 = *(const float4*)(kr);
      float4 a1 = *(const float4*)(kr + 4);
      float4 b0 = *(const float4*)(vr);
      float4 b1 = *(const float4*)(vr + 4);
      ks4[sr][dg*2]   = make_float4(a0.x+ppk0.x, a0.y+ppk0.y, a0.z+ppk0.z, a0.w+ppk0.w);
      ks4[sr][dg*2+1] = make_float4(a1.x+ppk1.x, a1.y+ppk1.y, a1.z+ppk1.z, a1.w+ppk1.w);
      vs4[sr][dg*2]   = make_float4(b0.x+ppv0.x, b0.y+ppv0.y, b0.z+ppv0.z, b0.w+ppv0.w);
      vs4[sr][dg*2+1] = make_float4(b1.x+ppv1.x, b1.y+ppv1.y, b1.z+ppv1.z, b1.w+ppv1.w);
    }
    __syncthreads();

    float s[16];
    float cmx = mx;
    #pragma unroll
    for (int jj = 0; jj < 16; ++jj) {
      int j = w * 16 + jj;
      float a = 0.f;
      #pragma unroll
      for (int i = 0; i < 8; ++i) {
        float4 kk = ks4[j][i];
        a = fmaf(qr[i*4+0], kk.x, a);
        a = fmaf(qr[i*4+1], kk.y, a);
        a = fmaf(qr[i*4+2], kk.z, a);
        a = fmaf(qr[i*4+3], kk.w, a);
      }
      s[jj] = a;
      cmx = fmaxf(cmx, a);
    }
    float scale = __expf(mx - cmx);
    l *= scale;
    #pragma unroll
    for (int d = 0; d < 32; ++d) acc[d] *= scale;
    #pragma unroll
    for (int jj = 0; jj < 16; ++jj) {
      int j = w * 16 + jj;
      float p = __expf(s[jj] - cmx);
      l += p;
      #pragma unroll
      for (int i = 0; i < 8; ++i) {
        float4 vv = vs4[j][i];
        acc[i*4+0] = fmaf(p, vv.x, acc[i*4+0]);
        acc[i*4+1] = fmaf(p, vv.y, acc[i*4+1]);
        acc[i*4+2] = fmaf(p, vv.z, acc[i*4+2]);
        acc[i*4+3] = fmaf(p, vv.w, acc[i*4+3]);
      }
    }
    mx = cmx;
  }

  sm[w][lane] = mx;
  sl[w][lane] = l;
  #pragma unroll
  for (int d = 0; d < 32; ++d) sacc[w][lane][d] = acc[d];
  __syncthreads();

  float M = fmaxf(fmaxf(sm[0][lane], sm[1][lane]), fmaxf(sm[2][lane], sm[3][lane]));
  float e0 = __expf(sm[0][lane] - M);
  float e1 = __expf(sm[1][lane] - M);
  float e2 = __expf(sm[2][lane] - M);
  float e3 = __expf(sm[3][lane] - M);
  float L = sl[0][lane]*e0 + sl[1][lane]*e1 + sl[2][lane]*e2 + sl[3][lane]*e3;
  float inv = 1.f / L;
  size_t base = (((size_t)bp * 64 + lane) * 256) + h * 32 + w * 8;
  #pragma unroll
  for (int dd = 0; dd < 8; ++dd) {
    int d = w * 8 + dd;
    float sv = sacc[0][lane][d]*e0 + sacc[1][lane][d]*e1
             + sacc[2][lane][d]*e2 + sacc[3][lane][d]*e3;
    o[base + dd] = __float2bfloat16(sv * inv);
  }
}

// ---------------------------------------------------------------------------
// scatter: out[pixel] = x[pixel] + prj[row]  (window reverse + residual)
// ---------------------------------------------------------------------------
__global__ __launch_bounds__(256) void scatter_kernel(
    const float* __restrict__ x, const float* __restrict__ prj,
    float* __restrict__ out, int b0) {
  int gid = blockIdx.x * 256 + threadIdx.x;
  int c = gid & 255;
  int r = gid >> 8;
  int n = r & 63;
  int t = (r >> 6) & 3;
  int b_l = r >> 8;
  int b_ = b0 + b_l;
  int b = b_ >> 6, wh = (b_ >> 3) & 7, ww = b_ & 7;
  int gh = wh * 8 + (n >> 3), gw = ww * 8 + (n & 7);
  size_t pix = (((size_t)(b * 4 + t) * 64 + gh) * 64 + gw) * 256 + c;
  out[pix] = x[pix] + prj[(size_t)r * 256 + c];
}

// ---------------------------------------------------------------------------
// Launch
// ---------------------------------------------------------------------------
extern "C" void kernel_launch(void* const* d_in, const int* in_sizes, int n_in,
                              void* d_out, int out_size, void* d_ws, size_t ws_size,
                              hipStream_t stream) {
  const float* x       = (const float*)d_in[0];
  const float* kv      = (const float*)d_in[1];
  const float* nq_g    = (const float*)d_in[3];
  const float* nq_b    = (const float*)d_in[4];
  const float* nk_g    = (const float*)d_in[5];
  const float* nk_b    = (const float*)d_in[6];
  const float* q_w     = (const float*)d_in[7];
  const float* q_b     = (const float*)d_in[8];
  const float* kv_w    = (const float*)d_in[9];
  const float* kv_b    = (const float*)d_in[10];
  const float* rpb     = (const float*)d_in[11];
  const float* pos_emb = (const float*)d_in[12];
  const float* pq_w    = (const float*)d_in[13];
  const float* pq_b    = (const float*)d_in[14];
  const float* pk_w    = (const float*)d_in[15];
  const float* pk_b    = (const float*)d_in[16];
  const float* pv_w    = (const float*)d_in[17];
  const float* pv_b    = (const float*)d_in[18];
  const float* po_w    = (const float*)d_in[19];
  const float* po_b    = (const float*)d_in[20];
  const float* proj_w  = (const float*)d_in[21];
  const float* proj_b  = (const float*)d_in[22];
  const float* n2_g    = (const float*)d_in[23];
  const float* n2_b    = (const float*)d_in[24];
  const float* mlp_w1  = (const float*)d_in[25];
  const float* mlp_b1  = (const float*)d_in[26];
  const float* mlp_w2  = (const float*)d_in[27];
  const float* mlp_b2  = (const float*)d_in[28];
  float* out = (float*)d_out;
  float* ws = (float*)d_ws;

  size_t wsF = ws_size / sizeof(float);
  float* pospk = ws;
  float* pospv = ws + 16384;
  __hip_bfloat16* wq_b    = (__hip_bfloat16*)(ws + 32768);
  __hip_bfloat16* wkv_b   = (__hip_bfloat16*)(ws + 65536);
  __hip_bfloat16* wpq_b   = (__hip_bfloat16*)(ws + 131072);
  __hip_bfloat16* wpk_b   = (__hip_bfloat16*)(ws + 163840);
  __hip_bfloat16* wpv_b   = (__hip_bfloat16*)(ws + 196608);
  __hip_bfloat16* wpo_b   = (__hip_bfloat16*)(ws + 229376);
  __hip_bfloat16* wproj_b = (__hip_bfloat16*)(ws + 262144);
  __hip_bfloat16* wm1_b   = (__hip_bfloat16*)(ws + 294912);
  __hip_bfloat16* wm2_b   = (__hip_bfloat16*)(ws + 425984);
  const size_t FIXED = 557056;

  int CH = 0;
  const int cands[7] = {64, 32, 16, 8, 4, 2, 1};
  for (int i = 0; i < 7; ++i) {
    size_t need = FIXED + (size_t)1179648 * cands[i];
    if (need <= wsF) { CH = cands[i]; break; }
  }
  if (CH == 0) return;
  size_t CHs = (size_t)CH;
  float* cb = ws + FIXED;

  __hip_bfloat16* qw_b  = (__hip_bfloat16*)cb;
  __hip_bfloat16* kvw_b = (__hip_bfloat16*)(cb + 32768 * CHs);
  float* qb2 = cb + 73728 * CHs;
  float* kvp = cb + 139264 * CHs;
  float* PK  = cb;
  float* PV  = cb + 327680 * CHs;
  __hip_bfloat16* xw_b  = (__hip_bfloat16*)(cb + 655360 * CHs);
  __hip_bfloat16* AVG_b = (__hip_bfloat16*)(cb + 819200 * CHs);
  float* PQ  = cb + 851968 * CHs;
  float* PKA = cb + 917504 * CHs;
  float* PVA = cb + 983040 * CHs;
  __hip_bfloat16* OC_b = (__hip_bfloat16*)(cb + 1048576 * CHs);
  __hip_bfloat16* PG_b = (__hip_bfloat16*)(cb + 1081344 * CHs);
  float* PRJ = cb + 1114112 * CHs;

  gemm_kernel<<<dim3(4, 1), 256, 0, stream>>>(pos_emb, pk_w, pk_b, pospk, 64, 256, 256);
  gemm_kernel<<<dim3(4, 1), 256, 0, stream>>>(pos_emb, pv_w, pv_b, pospv, 64, 256, 256);
  convb_kernel<<<256,  256, 0, stream>>>(q_w,    wq_b,    65536);
  convb_kernel<<<512,  256, 0, stream>>>(kv_w,   wkv_b,   131072);
  convb_kernel<<<256,  256, 0, stream>>>(pq_w,   wpq_b,   65536);
  convb_kernel<<<256,  256, 0, stream>>>(pk_w,   wpk_b,   65536);
  convb_kernel<<<256,  256, 0, stream>>>(pv_w,   wpv_b,   65536);
  convb_kernel<<<256,  256, 0, stream>>>(po_w,   wpo_b,   65536);
  convb_kernel<<<256,  256, 0, stream>>>(proj_w, wproj_b, 65536);
  convb_kernel<<<1024, 256, 0, stream>>>(mlp_w1, wm1_b,   262144);
  convb_kernel<<<1024, 256, 0, stream>>>(mlp_w2, wm2_b,   262144);

  for (int c0 = 0; c0 < 128; c0 += CH) {
    int rowsQ  = CH * 256;
    int rowsKV = CH * 320;
    int rowsXW = CH * 1280;
    int bpC    = CH * 4;
    int rowsP  = bpC * 64;
    ln_part_kernel<<<rowsQ, 256, 0, stream>>>(x, qw_b, nq_g, nq_b, 4, c0);
    ln_part_kernel<<<rowsKV, 256, 0, stream>>>(kv, kvw_b, nk_g, nk_b, 5, c0);
    mgemm_kernel<<<dim3(2, rowsQ / 128), 256, 0, stream>>>(
        (const ushort*)qw_b, (const ushort*)wq_b, q_b, nullptr, qb2, rowsQ, 256, 256, 0);
    mgemm_kernel<<<dim3(4, (rowsKV + 127) / 128), 256, 0, stream>>>(
        (const ushort*)kvw_b, (const ushort*)wkv_b, kv_b, nullptr, kvp, rowsKV, 512, 256, 0);
    wattn_kernel<<<CH * 40, 256, 0, stream>>>(qb2, kvp, rpb, xw_b);
    mgemm_kernel<<<dim3(2, rowsXW / 128), 256, 0, stream>>>(
        (const ushort*)xw_b, (const ushort*)wpk_b, nullptr, nullptr, PK, rowsXW, 256, 256, 0);
    mgemm_kernel<<<dim3(2, rowsXW / 128), 256, 0, stream>>>(
        (const ushort*)xw_b, (const ushort*)wpv_b, nullptr, nullptr, PV, rowsXW, 256, 256, 0);
    avg3_kernel<<<rowsP, 256, 0, stream>>>(xw_b, PK, PV, pos_emb, AVG_b, PKA, PVA);
    mgemm_kernel<<<dim3(2, rowsP / 128), 256, 0, stream>>>(
        (const ushort*)AVG_b, (const ushort*)wpq_b, pq_b, nullptr, PQ, rowsP, 256, 256, 0);
    pattn_kernel<<<bpC * 8, 256, 0, stream>>>(PQ, PK, PV, PKA, PVA, pospk, pospv, OC_b);
    mgemm_kernel<<<dim3(2, rowsP / 128), 256, 0, stream>>>(
        (const ushort*)OC_b, (const ushort*)wpo_b, po_b, nullptr, PG_b, rowsP, 256, 256, 3);
    mgemm_kernel<<<dim3(2, rowsP / 128), 256, 0, stream>>>(
        (const ushort*)PG_b, (const ushort*)wproj_b, proj_b, nullptr, PRJ, rowsP, 256, 256, 0);
    scatter_kernel<<<rowsP, 256, 0, stream>>>(x, PRJ, out, c0);
  }

  int R = 32768;
  while ((size_t)R * 640 > (size_t)1179648 * CHs && R > 128) R >>= 1;
  __hip_bfloat16* ln2c = (__hip_bfloat16*)cb;
  __hip_bfloat16* h1c  = (__hip_bfloat16*)(cb + 128 * (size_t)R);
  for (int r0 = 0; r0 < 32768; r0 += R) {
    ln_plain_kernel<<<R, 256, 0, stream>>>(out + (size_t)r0 * 256, ln2c, n2_g, n2_b);
    mgemm_kernel<<<dim3(8, R / 128), 256, 0, stream>>>(
        (const ushort*)ln2c, (const ushort*)wm1_b, mlp_b1, nullptr, h1c, R, 1024, 256, 3);
    mgemm_kernel<<<dim3(2, R / 128), 256, 0, stream>>>(
        (const ushort*)h1c, (const ushort*)wm2_b, mlp_b2, out + (size_t)r0 * 256,
        out + (size_t)r0 * 256, R, 256, 1024, 0);
  }
}

// Round 9
// 1845.698 us; speedup vs baseline: 2.8428x; 1.1771x over previous
//
#include <hip/hip_runtime.h>
#include <hip/hip_bf16.h>
#include <cstddef>
#include <cstdint>

#define SCALE_QK 0.17677669529663687f   // 32^-0.5

typedef __attribute__((ext_vector_type(8))) short bf16x8;
typedef __attribute__((ext_vector_type(4))) float f32x4;

// ---------------------------------------------------------------------------
// f32 -> bf16 conversion (weights)
// ---------------------------------------------------------------------------
__global__ __launch_bounds__(256) void convb_kernel(
    const float* __restrict__ src, __hip_bfloat16* __restrict__ dst, int n) {
  int i = blockIdx.x * 256 + threadIdx.x;
  if (i < n) dst[i] = __float2bfloat16(src[i]);
}

// ---------------------------------------------------------------------------
// rpb expansion: rpbx[h][n][j] (bf16) = rpb_table[rpi(n,j)*8+h], 8*64*64 entries
// ---------------------------------------------------------------------------
__global__ __launch_bounds__(256) void rpbx_kernel(
    const float* __restrict__ rpb_table, ushort* __restrict__ rpbx) {
  int gid = blockIdx.x * 256 + threadIdx.x;   // < 32768
  int h = gid >> 12;
  int rest = gid & 4095;
  int n = rest >> 6, j = rest & 63;
  int i1 = n >> 3, j1 = n & 7, i2 = j >> 3, j2 = j & 7;
  float v = rpb_table[((i1 - i2 + 7) * 15 + (j1 - j2 + 7)) * 8 + h];
  __hip_bfloat16 b = __float2bfloat16(v);
  rpbx[gid] = *reinterpret_cast<ushort*>(&b);
}

// ---------------------------------------------------------------------------
// LayerNorm + window partition -> bf16 rows
// ---------------------------------------------------------------------------
__global__ __launch_bounds__(256) void ln_part_kernel(
    const float* __restrict__ in, __hip_bfloat16* __restrict__ out,
    const float* __restrict__ gamma, const float* __restrict__ beta,
    int S, int b0) {
  int r = blockIdx.x;
  int n = r & 63;
  int tmp = r >> 6;
  int s = tmp % S;
  int b_ = b0 + tmp / S;
  int b  = b_ >> 6;
  int wh = (b_ >> 3) & 7;
  int ww = b_ & 7;
  int gh = wh * 8 + (n >> 3);
  int gw = ww * 8 + (n & 7);
  const float* src = in + (((size_t)(b * S + s) * 64 + gh) * 64 + gw) * 256;
  int c = threadIdx.x;
  float v = src[c];
  __shared__ float red[256];
  red[c] = v; __syncthreads();
  for (int off = 128; off > 0; off >>= 1) { if (c < off) red[c] += red[c + off]; __syncthreads(); }
  float mu = red[0] * (1.f / 256.f);
  __syncthreads();
  float dv = v - mu;
  red[c] = dv * dv; __syncthreads();
  for (int off = 128; off > 0; off >>= 1) { if (c < off) red[c] += red[c + off]; __syncthreads(); }
  float var = red[0] * (1.f / 256.f);
  out[(size_t)r * 256 + c] = __float2bfloat16(dv * rsqrtf(var + 1e-5f) * gamma[c] + beta[c]);
}

// Plain LayerNorm (f32 in) -> bf16 out
__global__ __launch_bounds__(256) void ln_plain_kernel(
    const float* __restrict__ in, __hip_bfloat16* __restrict__ out,
    const float* __restrict__ gamma, const float* __restrict__ beta) {
  int r = blockIdx.x;
  const float* src = in + (size_t)r * 256;
  int c = threadIdx.x;
  float v = src[c];
  __shared__ float red[256];
  red[c] = v; __syncthreads();
  for (int off = 128; off > 0; off >>= 1) { if (c < off) red[c] += red[c + off]; __syncthreads(); }
  float mu = red[0] * (1.f / 256.f);
  __syncthreads();
  float dv = v - mu;
  red[c] = dv * dv; __syncthreads();
  for (int off = 128; off > 0; off >>= 1) { if (c < off) red[c] += red[c + off]; __syncthreads(); }
  float var = red[0] * (1.f / 256.f);
  out[(size_t)r * 256 + c] = __float2bfloat16(dv * rsqrtf(var + 1e-5f) * gamma[c] + beta[c]);
}

// ---------------------------------------------------------------------------
// bf16 MFMA GEMM: C[M,N] = A[M,K](bf16) @ W[N,K](bf16)^T (+ bias)
// 128x128 tile, BK=64, 4 waves (2x2 of 64x64), 16x16x32 MFMA, XOR-swizzled LDS.
// flags: bit0 = gelu, bit1 = bf16 output. resid (f32) optional, f32-out only.
// ---------------------------------------------------------------------------
__global__ __launch_bounds__(256) void mgemm_kernel(
    const ushort* __restrict__ A, const ushort* __restrict__ W,
    const float* __restrict__ bias, const float* __restrict__ resid,
    void* __restrict__ Cp, int Mrows, int N, int K, int flags) {
  __shared__ ushort As[128 * 64];
  __shared__ ushort Bs[128 * 64];
  int tid = threadIdx.x;
  int lane = tid & 63, wid = tid >> 6;
  int wm = wid >> 1, wn = wid & 1;
  int row0 = blockIdx.y * 128, col0 = blockIdx.x * 128;
  int srow = tid >> 3;           // 0..31
  int slot = tid & 7;            // 16B slot within 128B row
  f32x4 acc[4][4];
  #pragma unroll
  for (int m = 0; m < 4; ++m)
    #pragma unroll
    for (int n = 0; n < 4; ++n) acc[m][n] = (f32x4){0.f, 0.f, 0.f, 0.f};

  for (int k0 = 0; k0 < K; k0 += 64) {
    #pragma unroll
    for (int i = 0; i < 4; ++i) {
      int r = i * 32 + srow;
      int gr = row0 + r; if (gr >= Mrows) gr = Mrows - 1;
      bf16x8 va = *(const bf16x8*)(A + (size_t)gr * K + k0 + slot * 8);
      int gc = col0 + r;
      bf16x8 vb = *(const bf16x8*)(W + (size_t)gc * K + k0 + slot * 8);
      int ldso = r * 64 + ((slot ^ (r & 7)) << 3);
      *(bf16x8*)(As + ldso) = va;
      *(bf16x8*)(Bs + ldso) = vb;
    }
    __syncthreads();
    #pragma unroll
    for (int ks = 0; ks < 2; ++ks) {
      bf16x8 af[4], bfr[4];
      int sgrp = ks * 4 + (lane >> 4);
      #pragma unroll
      for (int m = 0; m < 4; ++m) {
        int r = wm * 64 + m * 16 + (lane & 15);
        af[m] = *(const bf16x8*)(As + r * 64 + ((sgrp ^ (r & 7)) << 3));
      }
      #pragma unroll
      for (int n = 0; n < 4; ++n) {
        int r = wn * 64 + n * 16 + (lane & 15);
        bfr[n] = *(const bf16x8*)(Bs + r * 64 + ((sgrp ^ (r & 7)) << 3));
      }
      #pragma unroll
      for (int m = 0; m < 4; ++m)
        #pragma unroll
        for (int n = 0; n < 4; ++n)
          acc[m][n] = __builtin_amdgcn_mfma_f32_16x16x32_bf16(af[m], bfr[n], acc[m][n], 0, 0, 0);
    }
    __syncthreads();
  }

  float* Cf = (float*)Cp;
  __hip_bfloat16* Cb = (__hip_bfloat16*)Cp;
  #pragma unroll
  for (int m = 0; m < 4; ++m) {
    #pragma unroll
    for (int n = 0; n < 4; ++n) {
      int col = col0 + wn * 64 + n * 16 + (lane & 15);
      #pragma unroll
      for (int r = 0; r < 4; ++r) {
        int row = row0 + wm * 64 + m * 16 + (lane >> 4) * 4 + r;
        if (row >= Mrows) continue;
        float v = acc[m][n][r] + (bias ? bias[col] : 0.f);
        if (flags & 1) v = 0.5f * v * (1.f + erff(v * 0.70710678118654752f));
        if (resid) v += resid[(size_t)row * N + col];
        if (flags & 2) Cb[(size_t)row * N + col] = __float2bfloat16(v);
        else           Cf[(size_t)row * N + col] = v;
      }
    }
  }
}

// ---------------------------------------------------------------------------
// f32 GEMM (tiny 64-row pos_emb projections)
// ---------------------------------------------------------------------------
#define TBM 64
#define TBN 64
#define TBK 16
__global__ __launch_bounds__(256) void gemm_kernel(
    const float* __restrict__ A, const float* __restrict__ Wt,
    const float* __restrict__ bias, float* __restrict__ Cc,
    int Mrows, int Nout, int K) {
  __shared__ float Asl[TBK][TBM + 1];
  __shared__ float Wsl[TBK][TBN + 1];
  int tid = threadIdx.x;
  int tx = tid & 15, ty = tid >> 4;
  int row0 = blockIdx.y * TBM, col0 = blockIdx.x * TBN;
  float acc[4][4] = {};
  for (int k0 = 0; k0 < K; k0 += TBK) {
    #pragma unroll
    for (int t = 0; t < 4; ++t) {
      int idx = t * 256 + tid;
      int lm = idx >> 4, lk = idx & 15;
      int gr = row0 + lm;
      Asl[lk][lm] = (gr < Mrows) ? A[(size_t)gr * K + k0 + lk] : 0.f;
      int gc = col0 + lm;
      Wsl[lk][lm] = (gc < Nout) ? Wt[(size_t)gc * K + k0 + lk] : 0.f;
    }
    __syncthreads();
    #pragma unroll
    for (int kk = 0; kk < TBK; ++kk) {
      float a[4], b[4];
      #pragma unroll
      for (int i = 0; i < 4; ++i) a[i] = Asl[kk][ty * 4 + i];
      #pragma unroll
      for (int j = 0; j < 4; ++j) b[j] = Wsl[kk][tx * 4 + j];
      #pragma unroll
      for (int i = 0; i < 4; ++i)
        #pragma unroll
        for (int j = 0; j < 4; ++j)
          acc[i][j] = fmaf(a[i], b[j], acc[i][j]);
    }
    __syncthreads();
  }
  #pragma unroll
  for (int i = 0; i < 4; ++i) {
    int gr = row0 + ty * 4 + i;
    if (gr >= Mrows) continue;
    #pragma unroll
    for (int j = 0; j < 4; ++j) {
      int gc = col0 + tx * 4 + j;
      if (gc >= Nout) continue;
      Cc[(size_t)gr * Nout + gc] = acc[i][j] + bias[gc];
    }
  }
}

// ---------------------------------------------------------------------------
// Window attention v3: one block per (b_l, m, h), 256 threads = 4 waves (wave=t).
// Online softmax over 16-key strips (s[16] live, not s[64]); dual-accumulator
// QK dot for ILP; rpb staged from precomputed bf16 rpbx table. bf16 out.
// ---------------------------------------------------------------------------
__global__ __launch_bounds__(256) void wattn_kernel(
    const float* __restrict__ qb, const float* __restrict__ kvp,
    const ushort* __restrict__ rpbx, __hip_bfloat16* __restrict__ xw) {
  int idx = blockIdx.x;
  int h = idx & 7; idx >>= 3;
  int m = idx % 5;
  int b_l = idx / 5;
  int tid = threadIdx.x;
  int n = tid & 63;          // query index within window
  int w = tid >> 6;          // wave id = t

  __shared__ float4 ks4[64][9];
  __shared__ float4 vs4[64][9];
  __shared__ ushort rpbs[64][65];

  // stage K/V: thread stages row sr, d-slice [dg*8, dg*8+8)
  {
    int sr = tid >> 2, dg = tid & 3;
    const float* base = kvp + (((size_t)(b_l * 5 + m) * 64 + sr) * 512) + h * 32 + dg * 8;
    float4 k0 = *(const float4*)(base);
    float4 k1 = *(const float4*)(base + 4);
    float4 v0 = *(const float4*)(base + 256);
    float4 v1 = *(const float4*)(base + 260);
    ks4[sr][dg * 2]     = k0;
    ks4[sr][dg * 2 + 1] = k1;
    vs4[sr][dg * 2]     = v0;
    vs4[sr][dg * 2 + 1] = v1;
  }
  // stage rpb tile for head h (coalesced copy from precomputed table)
  {
    const ushort* rsrc = rpbx + h * 4096;
    #pragma unroll
    for (int e = tid; e < 4096; e += 256) rpbs[e >> 6][e & 63] = rsrc[e];
  }

  // load query row (t=w, query n)
  float qr[32];
  {
    const float* qrow = qb + (((size_t)(b_l * 4 + w) * 64 + n) * 256) + h * 32;
    #pragma unroll
    for (int i = 0; i < 8; ++i) {
      float4 qv = *(const float4*)(qrow + i * 4);
      qr[i*4+0] = qv.x * SCALE_QK; qr[i*4+1] = qv.y * SCALE_QK;
      qr[i*4+2] = qv.z * SCALE_QK; qr[i*4+3] = qv.w * SCALE_QK;
    }
  }
  __syncthreads();

  float mx = -1e30f, l = 0.f;
  float acc[32];
  #pragma unroll
  for (int d = 0; d < 32; ++d) acc[d] = 0.f;

  #pragma unroll
  for (int st = 0; st < 4; ++st) {
    float s[16];
    float cmx = mx;
    #pragma unroll
    for (int jj = 0; jj < 16; ++jj) {
      int j = st * 16 + jj;
      float a0 = 0.f, a1 = 0.f;    // dual chains for ILP
      #pragma unroll
      for (int i = 0; i < 4; ++i) {
        float4 k0 = ks4[j][i * 2];
        float4 k1 = ks4[j][i * 2 + 1];
        a0 = fmaf(qr[i*8+0], k0.x, a0);
        a0 = fmaf(qr[i*8+1], k0.y, a0);
        a0 = fmaf(qr[i*8+2], k0.z, a0);
        a0 = fmaf(qr[i*8+3], k0.w, a0);
        a1 = fmaf(qr[i*8+4], k1.x, a1);
        a1 = fmaf(qr[i*8+5], k1.y, a1);
        a1 = fmaf(qr[i*8+6], k1.z, a1);
        a1 = fmaf(qr[i*8+7], k1.w, a1);
      }
      ushort rb = rpbs[n][j];
      float bias = __bfloat162float(*reinterpret_cast<__hip_bfloat16*>(&rb));
      float sb = a0 + a1 + bias;
      s[jj] = sb;
      cmx = fmaxf(cmx, sb);
    }
    float sc = __expf(mx - cmx);
    l *= sc;
    #pragma unroll
    for (int d = 0; d < 32; ++d) acc[d] *= sc;
    #pragma unroll
    for (int jj = 0; jj < 16; ++jj) {
      int j = st * 16 + jj;
      float p = __expf(s[jj] - cmx);
      l += p;
      #pragma unroll
      for (int i = 0; i < 8; ++i) {
        float4 vv = vs4[j][i];
        acc[i*4+0] = fmaf(p, vv.x, acc[i*4+0]);
        acc[i*4+1] = fmaf(p, vv.y, acc[i*4+1]);
        acc[i*4+2] = fmaf(p, vv.z, acc[i*4+2]);
        acc[i*4+3] = fmaf(p, vv.w, acc[i*4+3]);
      }
    }
    mx = cmx;
  }
  float inv = 1.f / l;

  // scramble: f=m*4+t -> tp=f/5, mp=f%5 ; np=h*8+n/8 ; cp=(n%8)*32+d
  int f = m * 4 + w;
  int tp = f / 5, mp = f % 5;
  int np = h * 8 + (n >> 3);
  int cp = (n & 7) * 32;
  size_t base = ((((size_t)(b_l * 4 + tp) * 5 + mp) * 64 + np) * 256) + cp;
  #pragma unroll
  for (int d = 0; d < 32; ++d) xw[base + d] = __float2bfloat16(acc[d] * inv);
}

// ---------------------------------------------------------------------------
// avg3: avgq(bf16) = mean_m xw + pos ; pka/pva(f32) = mean_m PK/PV
// ---------------------------------------------------------------------------
__global__ __launch_bounds__(256) void avg3_kernel(
    const __hip_bfloat16* __restrict__ xw, const float* __restrict__ pk,
    const float* __restrict__ pv, const float* __restrict__ pos_emb,
    __hip_bfloat16* __restrict__ avgq, float* __restrict__ pka,
    float* __restrict__ pva) {
  int gid = blockIdx.x * 256 + threadIdx.x;
  int c = gid & 255;
  int rn = gid >> 8;
  int n = rn & 63;
  int bp = rn >> 6;
  size_t base = ((size_t)bp * 320 + n) * 256 + c;
  const size_t stride = 64 * 256;
  float sq = 0.f, sk = 0.f, sv = 0.f;
  #pragma unroll
  for (int m = 0; m < 5; ++m) {
    sq += __bfloat162float(xw[base + m * stride]);
    sk += pk[base + m * stride];
    sv += pv[base + m * stride];
  }
  avgq[(size_t)rn * 256 + c] = __float2bfloat16(sq * 0.2f + pos_emb[n * 256 + c]);
  pka[(size_t)rn * 256 + c] = sk * 0.2f;
  pva[(size_t)rn * 256 + c] = sv * 0.2f;
}

// ---------------------------------------------------------------------------
// Pool attention v2: one block per (bp_l, h), 256 threads = 4 waves.
// ---------------------------------------------------------------------------
__global__ __launch_bounds__(256) void pattn_kernel(
    const float* __restrict__ pq, const float* __restrict__ pk,
    const float* __restrict__ pv, const float* __restrict__ pka,
    const float* __restrict__ pva, const float* __restrict__ pos_pk,
    const float* __restrict__ pos_pv, __hip_bfloat16* __restrict__ o) {
  int h = blockIdx.x & 7;
  int bp = blockIdx.x >> 3;
  int tid = threadIdx.x;
  int lane = tid & 63;        // query index
  int w = tid >> 6;           // wave id -> key strip [w*16, w*16+16)
  __shared__ float4 ks4[64][9];
  __shared__ float4 vs4[64][9];
  __shared__ float sm[4][64];
  __shared__ float sl[4][64];
  __shared__ float sacc[4][64][32];

  int sr = tid >> 2, dg = tid & 3;
  const float* ppkp = pos_pk + sr * 256 + h * 32 + dg * 8;
  const float* ppvp = pos_pv + sr * 256 + h * 32 + dg * 8;
  float4 ppk0 = *(const float4*)(ppkp);
  float4 ppk1 = *(const float4*)(ppkp + 4);
  float4 ppv0 = *(const float4*)(ppvp);
  float4 ppv1 = *(const float4*)(ppvp + 4);

  float qr[32];
  {
    const float* qrow = pq + (((size_t)bp * 64 + lane) * 256) + h * 32;
    #pragma unroll
    for (int i = 0; i < 8; ++i) {
      float4 qv = *(const float4*)(qrow + i * 4);
      qr[i*4+0] = qv.x * SCALE_QK; qr[i*4+1] = qv.y * SCALE_QK;
      qr[i*4+2] = qv.z * SCALE_QK; qr[i*4+3] = qv.w * SCALE_QK;
    }
  }

  float mx = -1e30f, l = 0.f;
  float acc[32];
  #pragma unroll
  for (int d = 0; d < 32; ++d) acc[d] = 0.f;

  for (int mm = 0; mm < 6; ++mm) {
    const float* kr;
    const float* vr;
    if (mm == 0) {
      kr = pka + (((size_t)bp * 64 + sr) * 256) + h * 32 + dg * 8;
      vr = pva + (((size_t)bp * 64 + sr) * 256) + h * 32 + dg * 8;
    } else {
      kr = pk + (((size_t)(bp * 5 + mm - 1) * 64 + sr) * 256) + h * 32 + dg * 8;
      vr = pv + (((size_t)(bp * 5 + mm - 1) * 64 + sr) * 256) + h * 32 + dg * 8;
    }
    __syncthreads();
    {
      float4 a0 = *(const float4*)(kr);
      float4 a1 = *(const float4*)(kr + 4);
      float4 b0 = *(const float4*)(vr);
      float4 b1 = *(const float4*)(vr + 4);
      ks4[sr][dg*2]   = make_float4(a0.x+ppk0.x, a0.y+ppk0.y, a0.z+ppk0.z, a0.w+ppk0.w);
      ks4[sr][dg*2+1] = make_float4(a1.x+ppk1.x, a1.y+ppk1.y, a1.z+ppk1.z, a1.w+ppk1.w);
      vs4[sr][dg*2]   = make_float4(b0.x+ppv0.x, b0.y+ppv0.y, b0.z+ppv0.z, b0.w+ppv0.w);
      vs4[sr][dg*2+1] = make_float4(b1.x+ppv1.x, b1.y+ppv1.y, b1.z+ppv1.z, b1.w+ppv1.w);
    }
    __syncthreads();

    float s[16];
    float cmx = mx;
    #pragma unroll
    for (int jj = 0; jj < 16; ++jj) {
      int j = w * 16 + jj;
      float a = 0.f;
      #pragma unroll
      for (int i = 0; i < 8; ++i) {
        float4 kk = ks4[j][i];
        a = fmaf(qr[i*4+0], kk.x, a);
        a = fmaf(qr[i*4+1], kk.y, a);
        a = fmaf(qr[i*4+2], kk.z, a);
        a = fmaf(qr[i*4+3], kk.w, a);
      }
      s[jj] = a;
      cmx = fmaxf(cmx, a);
    }
    float scale = __expf(mx - cmx);
    l *= scale;
    #pragma unroll
    for (int d = 0; d < 32; ++d) acc[d] *= scale;
    #pragma unroll
    for (int jj = 0; jj < 16; ++jj) {
      int j = w * 16 + jj;
      float p = __expf(s[jj] - cmx);
      l += p;
      #pragma unroll
      for (int i = 0; i < 8; ++i) {
        float4 vv = vs4[j][i];
        acc[i*4+0] = fmaf(p, vv.x, acc[i*4+0]);
        acc[i*4+1] = fmaf(p, vv.y, acc[i*4+1]);
        acc[i*4+2] = fmaf(p, vv.z, acc[i*4+2]);
        acc[i*4+3] = fmaf(p, vv.w, acc[i*4+3]);
      }
    }
    mx = cmx;
  }

  sm[w][lane] = mx;
  sl[w][lane] = l;
  #pragma unroll
  for (int d = 0; d < 32; ++d) sacc[w][lane][d] = acc[d];
  __syncthreads();

  float M = fmaxf(fmaxf(sm[0][lane], sm[1][lane]), fmaxf(sm[2][lane], sm[3][lane]));
  float e0 = __expf(sm[0][lane] - M);
  float e1 = __expf(sm[1][lane] - M);
  float e2 = __expf(sm[2][lane] - M);
  float e3 = __expf(sm[3][lane] - M);
  float L = sl[0][lane]*e0 + sl[1][lane]*e1 + sl[2][lane]*e2 + sl[3][lane]*e3;
  float inv = 1.f / L;
  size_t base = (((size_t)bp * 64 + lane) * 256) + h * 32 + w * 8;
  #pragma unroll
  for (int dd = 0; dd < 8; ++dd) {
    int d = w * 8 + dd;
    float sv = sacc[0][lane][d]*e0 + sacc[1][lane][d]*e1
             + sacc[2][lane][d]*e2 + sacc[3][lane][d]*e3;
    o[base + dd] = __float2bfloat16(sv * inv);
  }
}

// ---------------------------------------------------------------------------
// scatter: out[pixel] = x[pixel] + prj[row]  (window reverse + residual)
// ---------------------------------------------------------------------------
__global__ __launch_bounds__(256) void scatter_kernel(
    const float* __restrict__ x, const float* __restrict__ prj,
    float* __restrict__ out, int b0) {
  int gid = blockIdx.x * 256 + threadIdx.x;
  int c = gid & 255;
  int r = gid >> 8;
  int n = r & 63;
  int t = (r >> 6) & 3;
  int b_l = r >> 8;
  int b_ = b0 + b_l;
  int b = b_ >> 6, wh = (b_ >> 3) & 7, ww = b_ & 7;
  int gh = wh * 8 + (n >> 3), gw = ww * 8 + (n & 7);
  size_t pix = (((size_t)(b * 4 + t) * 64 + gh) * 64 + gw) * 256 + c;
  out[pix] = x[pix] + prj[(size_t)r * 256 + c];
}

// ---------------------------------------------------------------------------
// Launch
// ---------------------------------------------------------------------------
extern "C" void kernel_launch(void* const* d_in, const int* in_sizes, int n_in,
                              void* d_out, int out_size, void* d_ws, size_t ws_size,
                              hipStream_t stream) {
  const float* x       = (const float*)d_in[0];
  const float* kv      = (const float*)d_in[1];
  const float* nq_g    = (const float*)d_in[3];
  const float* nq_b    = (const float*)d_in[4];
  const float* nk_g    = (const float*)d_in[5];
  const float* nk_b    = (const float*)d_in[6];
  const float* q_w     = (const float*)d_in[7];
  const float* q_b     = (const float*)d_in[8];
  const float* kv_w    = (const float*)d_in[9];
  const float* kv_b    = (const float*)d_in[10];
  const float* rpb     = (const float*)d_in[11];
  const float* pos_emb = (const float*)d_in[12];
  const float* pq_w    = (const float*)d_in[13];
  const float* pq_b    = (const float*)d_in[14];
  const float* pk_w    = (const float*)d_in[15];
  const float* pk_b    = (const float*)d_in[16];
  const float* pv_w    = (const float*)d_in[17];
  const float* pv_b    = (const float*)d_in[18];
  const float* po_w    = (const float*)d_in[19];
  const float* po_b    = (const float*)d_in[20];
  const float* proj_w  = (const float*)d_in[21];
  const float* proj_b  = (const float*)d_in[22];
  const float* n2_g    = (const float*)d_in[23];
  const float* n2_b    = (const float*)d_in[24];
  const float* mlp_w1  = (const float*)d_in[25];
  const float* mlp_b1  = (const float*)d_in[26];
  const float* mlp_w2  = (const float*)d_in[27];
  const float* mlp_b2  = (const float*)d_in[28];
  float* out = (float*)d_out;
  float* ws = (float*)d_ws;

  size_t wsF = ws_size / sizeof(float);
  float* pospk = ws;
  float* pospv = ws + 16384;
  __hip_bfloat16* wq_b    = (__hip_bfloat16*)(ws + 32768);
  __hip_bfloat16* wkv_b   = (__hip_bfloat16*)(ws + 65536);
  __hip_bfloat16* wpq_b   = (__hip_bfloat16*)(ws + 131072);
  __hip_bfloat16* wpk_b   = (__hip_bfloat16*)(ws + 163840);
  __hip_bfloat16* wpv_b   = (__hip_bfloat16*)(ws + 196608);
  __hip_bfloat16* wpo_b   = (__hip_bfloat16*)(ws + 229376);
  __hip_bfloat16* wproj_b = (__hip_bfloat16*)(ws + 262144);
  __hip_bfloat16* wm1_b   = (__hip_bfloat16*)(ws + 294912);
  __hip_bfloat16* wm2_b   = (__hip_bfloat16*)(ws + 425984);
  ushort* rpbx            = (ushort*)(ws + 557056);   // 32768 ushorts = 16384 f
  const size_t FIXED = 573440;

  int CH = 0;
  const int cands[7] = {64, 32, 16, 8, 4, 2, 1};
  for (int i = 0; i < 7; ++i) {
    size_t need = FIXED + (size_t)1179648 * cands[i];
    if (need <= wsF) { CH = cands[i]; break; }
  }
  if (CH == 0) return;
  size_t CHs = (size_t)CH;
  float* cb = ws + FIXED;

  __hip_bfloat16* qw_b  = (__hip_bfloat16*)cb;
  __hip_bfloat16* kvw_b = (__hip_bfloat16*)(cb + 32768 * CHs);
  float* qb2 = cb + 73728 * CHs;
  float* kvp = cb + 139264 * CHs;
  float* PK  = cb;
  float* PV  = cb + 327680 * CHs;
  __hip_bfloat16* xw_b  = (__hip_bfloat16*)(cb + 655360 * CHs);
  __hip_bfloat16* AVG_b = (__hip_bfloat16*)(cb + 819200 * CHs);
  float* PQ  = cb + 851968 * CHs;
  float* PKA = cb + 917504 * CHs;
  float* PVA = cb + 983040 * CHs;
  __hip_bfloat16* OC_b = (__hip_bfloat16*)(cb + 1048576 * CHs);
  __hip_bfloat16* PG_b = (__hip_bfloat16*)(cb + 1081344 * CHs);
  float* PRJ = cb + 1114112 * CHs;

  gemm_kernel<<<dim3(4, 1), 256, 0, stream>>>(pos_emb, pk_w, pk_b, pospk, 64, 256, 256);
  gemm_kernel<<<dim3(4, 1), 256, 0, stream>>>(pos_emb, pv_w, pv_b, pospv, 64, 256, 256);
  rpbx_kernel<<<128, 256, 0, stream>>>(rpb, rpbx);
  convb_kernel<<<256,  256, 0, stream>>>(q_w,    wq_b,    65536);
  convb_kernel<<<512,  256, 0, stream>>>(kv_w,   wkv_b,   131072);
  convb_kernel<<<256,  256, 0, stream>>>(pq_w,   wpq_b,   65536);
  convb_kernel<<<256,  256, 0, stream>>>(pk_w,   wpk_b,   65536);
  convb_kernel<<<256,  256, 0, stream>>>(pv_w,   wpv_b,   65536);
  convb_kernel<<<256,  256, 0, stream>>>(po_w,   wpo_b,   65536);
  convb_kernel<<<256,  256, 0, stream>>>(proj_w, wproj_b, 65536);
  convb_kernel<<<1024, 256, 0, stream>>>(mlp_w1, wm1_b,   262144);
  convb_kernel<<<1024, 256, 0, stream>>>(mlp_w2, wm2_b,   262144);

  for (int c0 = 0; c0 < 128; c0 += CH) {
    int rowsQ  = CH * 256;
    int rowsKV = CH * 320;
    int rowsXW = CH * 1280;
    int bpC    = CH * 4;
    int rowsP  = bpC * 64;
    ln_part_kernel<<<rowsQ, 256, 0, stream>>>(x, qw_b, nq_g, nq_b, 4, c0);
    ln_part_kernel<<<rowsKV, 256, 0, stream>>>(kv, kvw_b, nk_g, nk_b, 5, c0);
    mgemm_kernel<<<dim3(2, rowsQ / 128), 256, 0, stream>>>(
        (const ushort*)qw_b, (const ushort*)wq_b, q_b, nullptr, qb2, rowsQ, 256, 256, 0);
    mgemm_kernel<<<dim3(4, (rowsKV + 127) / 128), 256, 0, stream>>>(
        (const ushort*)kvw_b, (const ushort*)wkv_b, kv_b, nullptr, kvp, rowsKV, 512, 256, 0);
    wattn_kernel<<<CH * 40, 256, 0, stream>>>(qb2, kvp, rpbx, xw_b);
    mgemm_kernel<<<dim3(2, rowsXW / 128), 256, 0, stream>>>(
        (const ushort*)xw_b, (const ushort*)wpk_b, nullptr, nullptr, PK, rowsXW, 256, 256, 0);
    mgemm_kernel<<<dim3(2, rowsXW / 128), 256, 0, stream>>>(
        (const ushort*)xw_b, (const ushort*)wpv_b, nullptr, nullptr, PV, rowsXW, 256, 256, 0);
    avg3_kernel<<<rowsP, 256, 0, stream>>>(xw_b, PK, PV, pos_emb, AVG_b, PKA, PVA);
    mgemm_kernel<<<dim3(2, rowsP / 128), 256, 0, stream>>>(
        (const ushort*)AVG_b, (const ushort*)wpq_b, pq_b, nullptr, PQ, rowsP, 256, 256, 0);
    pattn_kernel<<<bpC * 8, 256, 0, stream>>>(PQ, PK, PV, PKA, PVA, pospk, pospv, OC_b);
    mgemm_kernel<<<dim3(2, rowsP / 128), 256, 0, stream>>>(
        (const ushort*)OC_b, (const ushort*)wpo_b, po_b, nullptr, PG_b, rowsP, 256, 256, 3);
    mgemm_kernel<<<dim3(2, rowsP / 128), 256, 0, stream>>>(
        (const ushort*)PG_b, (const ushort*)wproj_b, proj_b, nullptr, PRJ, rowsP, 256, 256, 0);
    scatter_kernel<<<rowsP, 256, 0, stream>>>(x, PRJ, out, c0);
  }

  int R = 32768;
  while ((size_t)R * 640 > (size_t)1179648 * CHs && R > 128) R >>= 1;
  __hip_bfloat16* ln2c = (__hip_bfloat16*)cb;
  __hip_bfloat16* h1c  = (__hip_bfloat16*)(cb + 128 * (size_t)R);
  for (int r0 = 0; r0 < 32768; r0 += R) {
    ln_plain_kernel<<<R, 256, 0, stream>>>(out + (size_t)r0 * 256, ln2c, n2_g, n2_b);
    mgemm_kernel<<<dim3(8, R / 128), 256, 0, stream>>>(
        (const ushort*)ln2c, (const ushort*)wm1_b, mlp_b1, nullptr, h1c, R, 1024, 256, 3);
    mgemm_kernel<<<dim3(2, R / 128), 256, 0, stream>>>(
        (const ushort*)h1c, (const ushort*)wm2_b, mlp_b2, out + (size_t)r0 * 256,
        out + (size_t)r0 * 256, R, 256, 1024, 0);
  }
}

// Round 10
// 1746.818 us; speedup vs baseline: 3.0037x; 1.0566x over previous
//
#include <hip/hip_runtime.h>
#include <hip/hip_bf16.h>
#include <cstddef>
#include <cstdint>

#define SCALE_QK 0.17677669529663687f   // 32^-0.5

typedef __attribute__((ext_vector_type(8))) short bf16x8;
typedef __attribute__((ext_vector_type(4))) float f32x4;

// ---------------------------------------------------------------------------
// f32 -> bf16 conversion (weights)
// ---------------------------------------------------------------------------
__global__ __launch_bounds__(256) void convb_kernel(
    const float* __restrict__ src, __hip_bfloat16* __restrict__ dst, int n) {
  int i = blockIdx.x * 256 + threadIdx.x;
  if (i < n) dst[i] = __float2bfloat16(src[i]);
}

// ---------------------------------------------------------------------------
// rpb expansion: rpbx[h][n][j] (bf16) = rpb_table[rpi(n,j)*8+h]
// ---------------------------------------------------------------------------
__global__ __launch_bounds__(256) void rpbx_kernel(
    const float* __restrict__ rpb_table, ushort* __restrict__ rpbx) {
  int gid = blockIdx.x * 256 + threadIdx.x;   // < 32768
  int h = gid >> 12;
  int rest = gid & 4095;
  int n = rest >> 6, j = rest & 63;
  int i1 = n >> 3, j1 = n & 7, i2 = j >> 3, j2 = j & 7;
  float v = rpb_table[((i1 - i2 + 7) * 15 + (j1 - j2 + 7)) * 8 + h];
  __hip_bfloat16 b = __float2bfloat16(v);
  rpbx[gid] = *reinterpret_cast<ushort*>(&b);
}

// ---------------------------------------------------------------------------
// LayerNorm + window partition -> bf16 rows
// ---------------------------------------------------------------------------
__global__ __launch_bounds__(256) void ln_part_kernel(
    const float* __restrict__ in, __hip_bfloat16* __restrict__ out,
    const float* __restrict__ gamma, const float* __restrict__ beta,
    int S, int b0) {
  int r = blockIdx.x;
  int n = r & 63;
  int tmp = r >> 6;
  int s = tmp % S;
  int b_ = b0 + tmp / S;
  int b  = b_ >> 6;
  int wh = (b_ >> 3) & 7;
  int ww = b_ & 7;
  int gh = wh * 8 + (n >> 3);
  int gw = ww * 8 + (n & 7);
  const float* src = in + (((size_t)(b * S + s) * 64 + gh) * 64 + gw) * 256;
  int c = threadIdx.x;
  float v = src[c];
  __shared__ float red[256];
  red[c] = v; __syncthreads();
  for (int off = 128; off > 0; off >>= 1) { if (c < off) red[c] += red[c + off]; __syncthreads(); }
  float mu = red[0] * (1.f / 256.f);
  __syncthreads();
  float dv = v - mu;
  red[c] = dv * dv; __syncthreads();
  for (int off = 128; off > 0; off >>= 1) { if (c < off) red[c] += red[c + off]; __syncthreads(); }
  float var = red[0] * (1.f / 256.f);
  out[(size_t)r * 256 + c] = __float2bfloat16(dv * rsqrtf(var + 1e-5f) * gamma[c] + beta[c]);
}

// Plain LayerNorm (f32 in) -> bf16 out
__global__ __launch_bounds__(256) void ln_plain_kernel(
    const float* __restrict__ in, __hip_bfloat16* __restrict__ out,
    const float* __restrict__ gamma, const float* __restrict__ beta) {
  int r = blockIdx.x;
  const float* src = in + (size_t)r * 256;
  int c = threadIdx.x;
  float v = src[c];
  __shared__ float red[256];
  red[c] = v; __syncthreads();
  for (int off = 128; off > 0; off >>= 1) { if (c < off) red[c] += red[c + off]; __syncthreads(); }
  float mu = red[0] * (1.f / 256.f);
  __syncthreads();
  float dv = v - mu;
  red[c] = dv * dv; __syncthreads();
  for (int off = 128; off > 0; off >>= 1) { if (c < off) red[c] += red[c + off]; __syncthreads(); }
  float var = red[0] * (1.f / 256.f);
  out[(size_t)r * 256 + c] = __float2bfloat16(dv * rsqrtf(var + 1e-5f) * gamma[c] + beta[c]);
}

// ---------------------------------------------------------------------------
// bf16 MFMA GEMM: C[M,N] = A[M,K](bf16) @ W[N,K](bf16)^T (+ bias)
// 128x128 tile, BK=64, 4 waves (2x2 of 64x64), 16x16x32 MFMA, XOR-swizzled LDS.
// flags: bit0 = gelu, bit1 = bf16 output. resid (f32) optional, f32-out only.
// ---------------------------------------------------------------------------
__global__ __launch_bounds__(256) void mgemm_kernel(
    const ushort* __restrict__ A, const ushort* __restrict__ W,
    const float* __restrict__ bias, const float* __restrict__ resid,
    void* __restrict__ Cp, int Mrows, int N, int K, int flags) {
  __shared__ ushort As[128 * 64];
  __shared__ ushort Bs[128 * 64];
  int tid = threadIdx.x;
  int lane = tid & 63, wid = tid >> 6;
  int wm = wid >> 1, wn = wid & 1;
  int row0 = blockIdx.y * 128, col0 = blockIdx.x * 128;
  int srow = tid >> 3;           // 0..31
  int slot = tid & 7;            // 16B slot within 128B row
  f32x4 acc[4][4];
  #pragma unroll
  for (int m = 0; m < 4; ++m)
    #pragma unroll
    for (int n = 0; n < 4; ++n) acc[m][n] = (f32x4){0.f, 0.f, 0.f, 0.f};

  for (int k0 = 0; k0 < K; k0 += 64) {
    #pragma unroll
    for (int i = 0; i < 4; ++i) {
      int r = i * 32 + srow;
      int gr = row0 + r; if (gr >= Mrows) gr = Mrows - 1;
      bf16x8 va = *(const bf16x8*)(A + (size_t)gr * K + k0 + slot * 8);
      int gc = col0 + r;
      bf16x8 vb = *(const bf16x8*)(W + (size_t)gc * K + k0 + slot * 8);
      int ldso = r * 64 + ((slot ^ (r & 7)) << 3);
      *(bf16x8*)(As + ldso) = va;
      *(bf16x8*)(Bs + ldso) = vb;
    }
    __syncthreads();
    #pragma unroll
    for (int ks = 0; ks < 2; ++ks) {
      bf16x8 af[4], bfr[4];
      int sgrp = ks * 4 + (lane >> 4);
      #pragma unroll
      for (int m = 0; m < 4; ++m) {
        int r = wm * 64 + m * 16 + (lane & 15);
        af[m] = *(const bf16x8*)(As + r * 64 + ((sgrp ^ (r & 7)) << 3));
      }
      #pragma unroll
      for (int n = 0; n < 4; ++n) {
        int r = wn * 64 + n * 16 + (lane & 15);
        bfr[n] = *(const bf16x8*)(Bs + r * 64 + ((sgrp ^ (r & 7)) << 3));
      }
      #pragma unroll
      for (int m = 0; m < 4; ++m)
        #pragma unroll
        for (int n = 0; n < 4; ++n)
          acc[m][n] = __builtin_amdgcn_mfma_f32_16x16x32_bf16(af[m], bfr[n], acc[m][n], 0, 0, 0);
    }
    __syncthreads();
  }

  float* Cf = (float*)Cp;
  __hip_bfloat16* Cb = (__hip_bfloat16*)Cp;
  #pragma unroll
  for (int m = 0; m < 4; ++m) {
    #pragma unroll
    for (int n = 0; n < 4; ++n) {
      int col = col0 + wn * 64 + n * 16 + (lane & 15);
      #pragma unroll
      for (int r = 0; r < 4; ++r) {
        int row = row0 + wm * 64 + m * 16 + (lane >> 4) * 4 + r;
        if (row >= Mrows) continue;
        float v = acc[m][n][r] + (bias ? bias[col] : 0.f);
        if (flags & 1) v = 0.5f * v * (1.f + erff(v * 0.70710678118654752f));
        if (resid) v += resid[(size_t)row * N + col];
        if (flags & 2) Cb[(size_t)row * N + col] = __float2bfloat16(v);
        else           Cf[(size_t)row * N + col] = v;
      }
    }
  }
}

// ---------------------------------------------------------------------------
// f32 GEMM (tiny 64-row pos_emb projections)
// ---------------------------------------------------------------------------
#define TBM 64
#define TBN 64
#define TBK 16
__global__ __launch_bounds__(256) void gemm_kernel(
    const float* __restrict__ A, const float* __restrict__ Wt,
    const float* __restrict__ bias, float* __restrict__ Cc,
    int Mrows, int Nout, int K) {
  __shared__ float Asl[TBK][TBM + 1];
  __shared__ float Wsl[TBK][TBN + 1];
  int tid = threadIdx.x;
  int tx = tid & 15, ty = tid >> 4;
  int row0 = blockIdx.y * TBM, col0 = blockIdx.x * TBN;
  float acc[4][4] = {};
  for (int k0 = 0; k0 < K; k0 += TBK) {
    #pragma unroll
    for (int t = 0; t < 4; ++t) {
      int idx = t * 256 + tid;
      int lm = idx >> 4, lk = idx & 15;
      int gr = row0 + lm;
      Asl[lk][lm] = (gr < Mrows) ? A[(size_t)gr * K + k0 + lk] : 0.f;
      int gc = col0 + lm;
      Wsl[lk][lm] = (gc < Nout) ? Wt[(size_t)gc * K + k0 + lk] : 0.f;
    }
    __syncthreads();
    #pragma unroll
    for (int kk = 0; kk < TBK; ++kk) {
      float a[4], b[4];
      #pragma unroll
      for (int i = 0; i < 4; ++i) a[i] = Asl[kk][ty * 4 + i];
      #pragma unroll
      for (int j = 0; j < 4; ++j) b[j] = Wsl[kk][tx * 4 + j];
      #pragma unroll
      for (int i = 0; i < 4; ++i)
        #pragma unroll
        for (int j = 0; j < 4; ++j)
          acc[i][j] = fmaf(a[i], b[j], acc[i][j]);
    }
    __syncthreads();
  }
  #pragma unroll
  for (int i = 0; i < 4; ++i) {
    int gr = row0 + ty * 4 + i;
    if (gr >= Mrows) continue;
    #pragma unroll
    for (int j = 0; j < 4; ++j) {
      int gc = col0 + tx * 4 + j;
      if (gc >= Nout) continue;
      Cc[(size_t)gr * Nout + gc] = acc[i][j] + bias[gc];
    }
  }
}

// ---------------------------------------------------------------------------
// Window attention v3: one block per (b_l, m, h), 256 threads = 4 waves (wave=t).
// Online softmax over 16-key strips; dual-accumulator QK dot; precomputed rpbx.
// ---------------------------------------------------------------------------
__global__ __launch_bounds__(256) void wattn_kernel(
    const float* __restrict__ qb, const float* __restrict__ kvp,
    const ushort* __restrict__ rpbx, __hip_bfloat16* __restrict__ xw) {
  int idx = blockIdx.x;
  int h = idx & 7; idx >>= 3;
  int m = idx % 5;
  int b_l = idx / 5;
  int tid = threadIdx.x;
  int n = tid & 63;          // query index within window
  int w = tid >> 6;          // wave id = t

  __shared__ float4 ks4[64][9];
  __shared__ float4 vs4[64][9];
  __shared__ ushort rpbs[64][65];

  {
    int sr = tid >> 2, dg = tid & 3;
    const float* base = kvp + (((size_t)(b_l * 5 + m) * 64 + sr) * 512) + h * 32 + dg * 8;
    float4 k0 = *(const float4*)(base);
    float4 k1 = *(const float4*)(base + 4);
    float4 v0 = *(const float4*)(base + 256);
    float4 v1 = *(const float4*)(base + 260);
    ks4[sr][dg * 2]     = k0;
    ks4[sr][dg * 2 + 1] = k1;
    vs4[sr][dg * 2]     = v0;
    vs4[sr][dg * 2 + 1] = v1;
  }
  {
    const ushort* rsrc = rpbx + h * 4096;
    #pragma unroll
    for (int e = tid; e < 4096; e += 256) rpbs[e >> 6][e & 63] = rsrc[e];
  }

  float qr[32];
  {
    const float* qrow = qb + (((size_t)(b_l * 4 + w) * 64 + n) * 256) + h * 32;
    #pragma unroll
    for (int i = 0; i < 8; ++i) {
      float4 qv = *(const float4*)(qrow + i * 4);
      qr[i*4+0] = qv.x * SCALE_QK; qr[i*4+1] = qv.y * SCALE_QK;
      qr[i*4+2] = qv.z * SCALE_QK; qr[i*4+3] = qv.w * SCALE_QK;
    }
  }
  __syncthreads();

  float mx = -1e30f, l = 0.f;
  float acc[32];
  #pragma unroll
  for (int d = 0; d < 32; ++d) acc[d] = 0.f;

  #pragma unroll
  for (int st = 0; st < 4; ++st) {
    float s[16];
    float cmx = mx;
    #pragma unroll
    for (int jj = 0; jj < 16; ++jj) {
      int j = st * 16 + jj;
      float a0 = 0.f, a1 = 0.f;
      #pragma unroll
      for (int i = 0; i < 4; ++i) {
        float4 k0 = ks4[j][i * 2];
        float4 k1 = ks4[j][i * 2 + 1];
        a0 = fmaf(qr[i*8+0], k0.x, a0);
        a0 = fmaf(qr[i*8+1], k0.y, a0);
        a0 = fmaf(qr[i*8+2], k0.z, a0);
        a0 = fmaf(qr[i*8+3], k0.w, a0);
        a1 = fmaf(qr[i*8+4], k1.x, a1);
        a1 = fmaf(qr[i*8+5], k1.y, a1);
        a1 = fmaf(qr[i*8+6], k1.z, a1);
        a1 = fmaf(qr[i*8+7], k1.w, a1);
      }
      ushort rb = rpbs[n][j];
      float bias = __bfloat162float(*reinterpret_cast<__hip_bfloat16*>(&rb));
      float sb = a0 + a1 + bias;
      s[jj] = sb;
      cmx = fmaxf(cmx, sb);
    }
    float sc = __expf(mx - cmx);
    l *= sc;
    #pragma unroll
    for (int d = 0; d < 32; ++d) acc[d] *= sc;
    #pragma unroll
    for (int jj = 0; jj < 16; ++jj) {
      int j = st * 16 + jj;
      float p = __expf(s[jj] - cmx);
      l += p;
      #pragma unroll
      for (int i = 0; i < 8; ++i) {
        float4 vv = vs4[j][i];
        acc[i*4+0] = fmaf(p, vv.x, acc[i*4+0]);
        acc[i*4+1] = fmaf(p, vv.y, acc[i*4+1]);
        acc[i*4+2] = fmaf(p, vv.z, acc[i*4+2]);
        acc[i*4+3] = fmaf(p, vv.w, acc[i*4+3]);
      }
    }
    mx = cmx;
  }
  float inv = 1.f / l;

  int f = m * 4 + w;
  int tp = f / 5, mp = f % 5;
  int np = h * 8 + (n >> 3);
  int cp = (n & 7) * 32;
  size_t base = ((((size_t)(b_l * 4 + tp) * 5 + mp) * 64 + np) * 256) + cp;
  #pragma unroll
  for (int d = 0; d < 32; ++d) xw[base + d] = __float2bfloat16(acc[d] * inv);
}

// ---------------------------------------------------------------------------
// avg3: avgq(bf16) = mean_m xw + pos ; pka/pva(f32) = mean_m PK/PV
// ---------------------------------------------------------------------------
__global__ __launch_bounds__(256) void avg3_kernel(
    const __hip_bfloat16* __restrict__ xw, const float* __restrict__ pk,
    const float* __restrict__ pv, const float* __restrict__ pos_emb,
    __hip_bfloat16* __restrict__ avgq, float* __restrict__ pka,
    float* __restrict__ pva) {
  int gid = blockIdx.x * 256 + threadIdx.x;
  int c = gid & 255;
  int rn = gid >> 8;
  int n = rn & 63;
  int bp = rn >> 6;
  size_t base = ((size_t)bp * 320 + n) * 256 + c;
  const size_t stride = 64 * 256;
  float sq = 0.f, sk = 0.f, sv = 0.f;
  #pragma unroll
  for (int m = 0; m < 5; ++m) {
    sq += __bfloat162float(xw[base + m * stride]);
    sk += pk[base + m * stride];
    sv += pv[base + m * stride];
  }
  avgq[(size_t)rn * 256 + c] = __float2bfloat16(sq * 0.2f + pos_emb[n * 256 + c]);
  pka[(size_t)rn * 256 + c] = sk * 0.2f;
  pva[(size_t)rn * 256 + c] = sv * 0.2f;
}

// ---------------------------------------------------------------------------
// Pool attention v3: one block per (bp_l, h), 512 threads = 8 waves.
// Wave w owns queries [8w, 8w+8); lane = (q, kg); lane processes keys == kg
// mod 8 (48 keys). Merge of 8 partials via __shfl_xor — no LDS merge buffer.
// ---------------------------------------------------------------------------
__global__ __launch_bounds__(512) void pattn_kernel(
    const float* __restrict__ pq, const float* __restrict__ pk,
    const float* __restrict__ pv, const float* __restrict__ pka,
    const float* __restrict__ pva, const float* __restrict__ pos_pk,
    const float* __restrict__ pos_pv, __hip_bfloat16* __restrict__ o) {
  int h = blockIdx.x & 7;
  int bp = blockIdx.x >> 3;
  int tid = threadIdx.x;
  int lane = tid & 63;
  int w = tid >> 6;                 // wave 0..7
  int q = w * 8 + (lane >> 3);      // query 0..63
  int kg = lane & 7;                // key subgroup

  __shared__ float4 ks4[64][9];
  __shared__ float4 vs4[64][9];

  // staging assignment: thread stages row sr, float4 slot dg
  int sr = tid >> 3, dg = tid & 7;
  const float* ppkp = pos_pk + sr * 256 + h * 32 + dg * 4;
  const float* ppvp = pos_pv + sr * 256 + h * 32 + dg * 4;
  float4 ppk = *(const float4*)(ppkp);
  float4 ppv = *(const float4*)(ppvp);

  float qr[32];
  {
    const float* qrow = pq + (((size_t)bp * 64 + q) * 256) + h * 32;
    #pragma unroll
    for (int i = 0; i < 8; ++i) {
      float4 qv = *(const float4*)(qrow + i * 4);
      qr[i*4+0] = qv.x * SCALE_QK; qr[i*4+1] = qv.y * SCALE_QK;
      qr[i*4+2] = qv.z * SCALE_QK; qr[i*4+3] = qv.w * SCALE_QK;
    }
  }

  float mx = -1e30f, l = 0.f;
  float acc[32];
  #pragma unroll
  for (int d = 0; d < 32; ++d) acc[d] = 0.f;

  for (int mm = 0; mm < 6; ++mm) {
    const float* kr;
    const float* vr;
    if (mm == 0) {
      kr = pka + (((size_t)bp * 64 + sr) * 256) + h * 32 + dg * 4;
      vr = pva + (((size_t)bp * 64 + sr) * 256) + h * 32 + dg * 4;
    } else {
      kr = pk + (((size_t)(bp * 5 + mm - 1) * 64 + sr) * 256) + h * 32 + dg * 4;
      vr = pv + (((size_t)(bp * 5 + mm - 1) * 64 + sr) * 256) + h * 32 + dg * 4;
    }
    __syncthreads();   // previous chunk fully consumed
    {
      float4 a = *(const float4*)(kr);
      float4 b = *(const float4*)(vr);
      ks4[sr][dg] = make_float4(a.x + ppk.x, a.y + ppk.y, a.z + ppk.z, a.w + ppk.w);
      vs4[sr][dg] = make_float4(b.x + ppv.x, b.y + ppv.y, b.z + ppv.z, b.w + ppv.w);
    }
    __syncthreads();

    // this lane's 8 keys in this chunk: j = s*8 + kg
    float s8[8];
    float cmx = mx;
    #pragma unroll
    for (int ss = 0; ss < 8; ++ss) {
      int j = ss * 8 + kg;
      float a0 = 0.f, a1 = 0.f;
      #pragma unroll
      for (int i = 0; i < 4; ++i) {
        float4 k0 = ks4[j][i * 2];
        float4 k1 = ks4[j][i * 2 + 1];
        a0 = fmaf(qr[i*8+0], k0.x, a0);
        a0 = fmaf(qr[i*8+1], k0.y, a0);
        a0 = fmaf(qr[i*8+2], k0.z, a0);
        a0 = fmaf(qr[i*8+3], k0.w, a0);
        a1 = fmaf(qr[i*8+4], k1.x, a1);
        a1 = fmaf(qr[i*8+5], k1.y, a1);
        a1 = fmaf(qr[i*8+6], k1.z, a1);
        a1 = fmaf(qr[i*8+7], k1.w, a1);
      }
      float sb = a0 + a1;
      s8[ss] = sb;
      cmx = fmaxf(cmx, sb);
    }
    float sc = __expf(mx - cmx);
    l *= sc;
    #pragma unroll
    for (int d = 0; d < 32; ++d) acc[d] *= sc;
    #pragma unroll
    for (int ss = 0; ss < 8; ++ss) {
      int j = ss * 8 + kg;
      float p = __expf(s8[ss] - cmx);
      l += p;
      #pragma unroll
      for (int i = 0; i < 8; ++i) {
        float4 vv = vs4[j][i];
        acc[i*4+0] = fmaf(p, vv.x, acc[i*4+0]);
        acc[i*4+1] = fmaf(p, vv.y, acc[i*4+1]);
        acc[i*4+2] = fmaf(p, vv.z, acc[i*4+2]);
        acc[i*4+3] = fmaf(p, vv.w, acc[i*4+3]);
      }
    }
    mx = cmx;
  }

  // merge 8 per-lane partials (same query) via shfl_xor over kg bits
  #pragma unroll
  for (int mask = 1; mask < 8; mask <<= 1) {
    float mo = __shfl_xor(mx, mask);
    float lo = __shfl_xor(l, mask);
    float M = fmaxf(mx, mo);
    float es = __expf(mx - M);
    float eo = __expf(mo - M);
    l = l * es + lo * eo;
    #pragma unroll
    for (int d = 0; d < 32; ++d) {
      float ao = __shfl_xor(acc[d], mask);
      acc[d] = acc[d] * es + ao * eo;
    }
    mx = M;
  }
  float inv = 1.f / l;

  // lane kg writes dims [kg*4, kg*4+4)
  size_t base = (((size_t)bp * 64 + q) * 256) + h * 32 + kg * 4;
  #pragma unroll
  for (int dd = 0; dd < 4; ++dd)
    o[base + dd] = __float2bfloat16(acc[kg * 4 + dd] * inv);
}

// ---------------------------------------------------------------------------
// scatter: out[pixel] = x[pixel] + prj[row]  (window reverse + residual)
// ---------------------------------------------------------------------------
__global__ __launch_bounds__(256) void scatter_kernel(
    const float* __restrict__ x, const float* __restrict__ prj,
    float* __restrict__ out, int b0) {
  int gid = blockIdx.x * 256 + threadIdx.x;
  int c = gid & 255;
  int r = gid >> 8;
  int n = r & 63;
  int t = (r >> 6) & 3;
  int b_l = r >> 8;
  int b_ = b0 + b_l;
  int b = b_ >> 6, wh = (b_ >> 3) & 7, ww = b_ & 7;
  int gh = wh * 8 + (n >> 3), gw = ww * 8 + (n & 7);
  size_t pix = (((size_t)(b * 4 + t) * 64 + gh) * 64 + gw) * 256 + c;
  out[pix] = x[pix] + prj[(size_t)r * 256 + c];
}

// ---------------------------------------------------------------------------
// Launch
// ---------------------------------------------------------------------------
extern "C" void kernel_launch(void* const* d_in, const int* in_sizes, int n_in,
                              void* d_out, int out_size, void* d_ws, size_t ws_size,
                              hipStream_t stream) {
  const float* x       = (const float*)d_in[0];
  const float* kv      = (const float*)d_in[1];
  const float* nq_g    = (const float*)d_in[3];
  const float* nq_b    = (const float*)d_in[4];
  const float* nk_g    = (const float*)d_in[5];
  const float* nk_b    = (const float*)d_in[6];
  const float* q_w     = (const float*)d_in[7];
  const float* q_b     = (const float*)d_in[8];
  const float* kv_w    = (const float*)d_in[9];
  const float* kv_b    = (const float*)d_in[10];
  const float* rpb     = (const float*)d_in[11];
  const float* pos_emb = (const float*)d_in[12];
  const float* pq_w    = (const float*)d_in[13];
  const float* pq_b    = (const float*)d_in[14];
  const float* pk_w    = (const float*)d_in[15];
  const float* pk_b    = (const float*)d_in[16];
  const float* pv_w    = (const float*)d_in[17];
  const float* pv_b    = (const float*)d_in[18];
  const float* po_w    = (const float*)d_in[19];
  const float* po_b    = (const float*)d_in[20];
  const float* proj_w  = (const float*)d_in[21];
  const float* proj_b  = (const float*)d_in[22];
  const float* n2_g    = (const float*)d_in[23];
  const float* n2_b    = (const float*)d_in[24];
  const float* mlp_w1  = (const float*)d_in[25];
  const float* mlp_b1  = (const float*)d_in[26];
  const float* mlp_w2  = (const float*)d_in[27];
  const float* mlp_b2  = (const float*)d_in[28];
  float* out = (float*)d_out;
  float* ws = (float*)d_ws;

  size_t wsF = ws_size / sizeof(float);
  float* pospk = ws;
  float* pospv = ws + 16384;
  __hip_bfloat16* wq_b    = (__hip_bfloat16*)(ws + 32768);
  __hip_bfloat16* wkv_b   = (__hip_bfloat16*)(ws + 65536);
  __hip_bfloat16* wpq_b   = (__hip_bfloat16*)(ws + 131072);
  __hip_bfloat16* wpk_b   = (__hip_bfloat16*)(ws + 163840);
  __hip_bfloat16* wpv_b   = (__hip_bfloat16*)(ws + 196608);
  __hip_bfloat16* wpo_b   = (__hip_bfloat16*)(ws + 229376);
  __hip_bfloat16* wproj_b = (__hip_bfloat16*)(ws + 262144);
  __hip_bfloat16* wm1_b   = (__hip_bfloat16*)(ws + 294912);
  __hip_bfloat16* wm2_b   = (__hip_bfloat16*)(ws + 425984);
  ushort* rpbx            = (ushort*)(ws + 557056);   // 32768 ushorts
  const size_t FIXED = 573440;

  int CH = 0;
  const int cands[7] = {64, 32, 16, 8, 4, 2, 1};
  for (int i = 0; i < 7; ++i) {
    size_t need = FIXED + (size_t)1179648 * cands[i];
    if (need <= wsF) { CH = cands[i]; break; }
  }
  if (CH == 0) return;
  size_t CHs = (size_t)CH;
  float* cb = ws + FIXED;

  __hip_bfloat16* qw_b  = (__hip_bfloat16*)cb;
  __hip_bfloat16* kvw_b = (__hip_bfloat16*)(cb + 32768 * CHs);
  float* qb2 = cb + 73728 * CHs;
  float* kvp = cb + 139264 * CHs;
  float* PK  = cb;
  float* PV  = cb + 327680 * CHs;
  __hip_bfloat16* xw_b  = (__hip_bfloat16*)(cb + 655360 * CHs);
  __hip_bfloat16* AVG_b = (__hip_bfloat16*)(cb + 819200 * CHs);
  float* PQ  = cb + 851968 * CHs;
  float* PKA = cb + 917504 * CHs;
  float* PVA = cb + 983040 * CHs;
  __hip_bfloat16* OC_b = (__hip_bfloat16*)(cb + 1048576 * CHs);
  __hip_bfloat16* PG_b = (__hip_bfloat16*)(cb + 1081344 * CHs);
  float* PRJ = cb + 1114112 * CHs;

  gemm_kernel<<<dim3(4, 1), 256, 0, stream>>>(pos_emb, pk_w, pk_b, pospk, 64, 256, 256);
  gemm_kernel<<<dim3(4, 1), 256, 0, stream>>>(pos_emb, pv_w, pv_b, pospv, 64, 256, 256);
  rpbx_kernel<<<128, 256, 0, stream>>>(rpb, rpbx);
  convb_kernel<<<256,  256, 0, stream>>>(q_w,    wq_b,    65536);
  convb_kernel<<<512,  256, 0, stream>>>(kv_w,   wkv_b,   131072);
  convb_kernel<<<256,  256, 0, stream>>>(pq_w,   wpq_b,   65536);
  convb_kernel<<<256,  256, 0, stream>>>(pk_w,   wpk_b,   65536);
  convb_kernel<<<256,  256, 0, stream>>>(pv_w,   wpv_b,   65536);
  convb_kernel<<<256,  256, 0, stream>>>(po_w,   wpo_b,   65536);
  convb_kernel<<<256,  256, 0, stream>>>(proj_w, wproj_b, 65536);
  convb_kernel<<<1024, 256, 0, stream>>>(mlp_w1, wm1_b,   262144);
  convb_kernel<<<1024, 256, 0, stream>>>(mlp_w2, wm2_b,   262144);

  for (int c0 = 0; c0 < 128; c0 += CH) {
    int rowsQ  = CH * 256;
    int rowsKV = CH * 320;
    int rowsXW = CH * 1280;
    int bpC    = CH * 4;
    int rowsP  = bpC * 64;
    ln_part_kernel<<<rowsQ, 256, 0, stream>>>(x, qw_b, nq_g, nq_b, 4, c0);
    ln_part_kernel<<<rowsKV, 256, 0, stream>>>(kv, kvw_b, nk_g, nk_b, 5, c0);
    mgemm_kernel<<<dim3(2, rowsQ / 128), 256, 0, stream>>>(
        (const ushort*)qw_b, (const ushort*)wq_b, q_b, nullptr, qb2, rowsQ, 256, 256, 0);
    mgemm_kernel<<<dim3(4, (rowsKV + 127) / 128), 256, 0, stream>>>(
        (const ushort*)kvw_b, (const ushort*)wkv_b, kv_b, nullptr, kvp, rowsKV, 512, 256, 0);
    wattn_kernel<<<CH * 40, 256, 0, stream>>>(qb2, kvp, rpbx, xw_b);
    mgemm_kernel<<<dim3(2, rowsXW / 128), 256, 0, stream>>>(
        (const ushort*)xw_b, (const ushort*)wpk_b, nullptr, nullptr, PK, rowsXW, 256, 256, 0);
    mgemm_kernel<<<dim3(2, rowsXW / 128), 256, 0, stream>>>(
        (const ushort*)xw_b, (const ushort*)wpv_b, nullptr, nullptr, PV, rowsXW, 256, 256, 0);
    avg3_kernel<<<rowsP, 256, 0, stream>>>(xw_b, PK, PV, pos_emb, AVG_b, PKA, PVA);
    mgemm_kernel<<<dim3(2, rowsP / 128), 256, 0, stream>>>(
        (const ushort*)AVG_b, (const ushort*)wpq_b, pq_b, nullptr, PQ, rowsP, 256, 256, 0);
    pattn_kernel<<<bpC * 8, 512, 0, stream>>>(PQ, PK, PV, PKA, PVA, pospk, pospv, OC_b);
    mgemm_kernel<<<dim3(2, rowsP / 128), 256, 0, stream>>>(
        (const ushort*)OC_b, (const ushort*)wpo_b, po_b, nullptr, PG_b, rowsP, 256, 256, 3);
    mgemm_kernel<<<dim3(2, rowsP / 128), 256, 0, stream>>>(
        (const ushort*)PG_b, (const ushort*)wproj_b, proj_b, nullptr, PRJ, rowsP, 256, 256, 0);
    scatter_kernel<<<rowsP, 256, 0, stream>>>(x, PRJ, out, c0);
  }

  int R = 32768;
  while ((size_t)R * 640 > (size_t)1179648 * CHs && R > 128) R >>= 1;
  __hip_bfloat16* ln2c = (__hip_bfloat16*)cb;
  __hip_bfloat16* h1c  = (__hip_bfloat16*)(cb + 128 * (size_t)R);
  for (int r0 = 0; r0 < 32768; r0 += R) {
    ln_plain_kernel<<<R, 256, 0, stream>>>(out + (size_t)r0 * 256, ln2c, n2_g, n2_b);
    mgemm_kernel<<<dim3(8, R / 128), 256, 0, stream>>>(
        (const ushort*)ln2c, (const ushort*)wm1_b, mlp_b1, nullptr, h1c, R, 1024, 256, 3);
    mgemm_kernel<<<dim3(2, R / 128), 256, 0, stream>>>(
        (const ushort*)h1c, (const ushort*)wm2_b, mlp_b2, out + (size_t)r0 * 256,
        out + (size_t)r0 * 256, R, 256, 1024, 0);
  }
}